// Round 11
// baseline (289.911 us; speedup 1.0000x reference)
//
#include <hip/hip_runtime.h>
#include <stdint.h>

typedef unsigned short u16;
typedef __attribute__((ext_vector_type(4))) float f32x4;
typedef __attribute__((ext_vector_type(16))) float f32x16;
typedef __attribute__((ext_vector_type(8))) short bf16x8;
typedef __attribute__((ext_vector_type(4))) unsigned short u16x4;
typedef __attribute__((ext_vector_type(8))) unsigned short u16x8;
typedef __attribute__((ext_vector_type(4))) unsigned u32x4;

static __device__ __forceinline__ u16 f2bf(float f) {
  union { float f; unsigned u; } v; v.f = f;
  unsigned r = v.u + 0x7fffu + ((v.u >> 16) & 1u);
  return (u16)(r >> 16);
}
static __device__ __forceinline__ float bf2f(u16 u) {
  union { unsigned u; float f; } v; v.u = ((unsigned)u) << 16;
  return v.f;
}

static __device__ __forceinline__ unsigned cvtpk(float lo, float hi) {
  unsigned r;
  asm("v_cvt_pk_bf16_f32 %0, %1, %2" : "=v"(r) : "v"(lo), "v"(hi));
  return r;
}

static __device__ __forceinline__ void plane32_swap(unsigned& a, unsigned& b) {
  asm volatile("v_permlane32_swap_b32 %0, %1" : "+v"(a), "+v"(b));
}

static __device__ __forceinline__ float exp2_fast(float x) {
  float r;
  asm("v_exp_f32 %0, %1" : "=v"(r) : "v"(x));
  return r;
}

static __device__ __forceinline__ void load_lds16(const void* g, void* l) {
  __builtin_amdgcn_global_load_lds(
      (const __attribute__((address_space(1))) void*)g,
      (__attribute__((address_space(3))) void*)l, 16, 0, 0);
}

// ---------------- conversion kernels ----------------

__global__ __launch_bounds__(256) void cvt_f32_bf16(
    const float* __restrict__ in, u16* __restrict__ out, int n) {
  int i = blockIdx.x * 256 + threadIdx.x;
  const int n4 = n >> 2;
  for (; i < n4; i += gridDim.x * 256) {
    f32x4 v = *(const f32x4*)(in + (size_t)i * 4);
    u16x4 o = { f2bf(v[0]), f2bf(v[1]), f2bf(v[2]), f2bf(v[3]) };
    *(u16x4*)(out + (size_t)i * 4) = o;
  }
}

__global__ __launch_bounds__(256) void build_wcat(
    const float* __restrict__ Wq, const float* __restrict__ Wk,
    const float* __restrict__ Wv, u16* __restrict__ out) {
  int i = blockIdx.x * 256 + threadIdx.x;
  const int n4 = 3072 * 512;
  for (; i < n4; i += gridDim.x * 256) {
    int row = i >> 9;
    int c4 = i & 511;
    const float* src;
    if (row < 2048)       src = Wq + (size_t)row * 2048;
    else if (row < 2560)  src = Wk + (size_t)(row - 2048) * 2048;
    else                  src = Wv + (size_t)(row - 2560) * 2048;
    f32x4 v = *(const f32x4*)(src + c4 * 4);
    u16x4 o = { f2bf(v[0]), f2bf(v[1]), f2bf(v[2]), f2bf(v[3]) };
    *(u16x4*)(out + (size_t)i * 4) = o;
  }
}

// ---------------- fused QKV GEMM + RMSNorm + RoPE + V-transpose ----------------------
// Main loop = m97 gemm_bt (XCD-localized). Epilogue VECTORIZED (R10 was scalar: +60us):
// tile stride 136 u16 (272 B -> every row 16B-aligned; q-reads 2-way bank = free).
// q/k: row sum-sq -> LDS row-major tile -> 8 iters of b128 reads + rope -> u16x8 stores.
// v: tile stored TRANSPOSED [d][tok] (scalar writes 2-way), read u16x8 along tok, store
// 16B coalesced to vt[d][t].
__global__ __launch_bounds__(256) void gemm_qkv(
    const u16* __restrict__ A, const u16* __restrict__ W,
    const float* __restrict__ qn_w, const float* __restrict__ kn_w,
    const float* __restrict__ cosb, const float* __restrict__ sinb,
    u16* __restrict__ qh, u16* __restrict__ kh, u16* __restrict__ vt) {
  const int K = 2048;
  __shared__ __align__(16) u16 smem[128 * 136];  // staging As/Bs; epilogue tile
  __shared__ float ssbuf[128][2];
  u16* As = smem;
  u16* Bs = smem + 4096;
  const int tid = threadIdx.x;
  const int lin = blockIdx.x;              // 768 blocks
  const int x = lin & 7, t = lin >> 3;     // XCD-localized bm panels
  const int bm = x * 4 + (t & 3);          // 0..31 token block
  const int bn = t >> 2;                   // 0..23 head block
  const int w = tid >> 6, l = tid & 63;
  const int wr = w >> 1, wc = w & 1;
  const int lr = l & 15, lg = l >> 4;
  f32x4 acc[4][4] = {};
  const int srow = tid >> 2;
  const int scol = (tid & 3) << 3;
  const u16* Ag = A + (size_t)bm * 128 * K + (size_t)srow * K + scol;
  const u16* Bg = W + (size_t)bn * 128 * K + (size_t)srow * K + scol;
  u16* Asl = As + srow * 32 + scol;
  u16* Bsl = Bs + srow * 32 + scol;
  for (int kt = 0; kt < 64; ++kt) {
    __syncthreads();
    const int ko = kt << 5;
    load_lds16(Ag + ko, Asl);
    load_lds16(Ag + (size_t)64 * K + ko, Asl + 64 * 32);
    load_lds16(Bg + ko, Bsl);
    load_lds16(Bg + (size_t)64 * K + ko, Bsl + 64 * 32);
    __syncthreads();
    bf16x8 af[4], bfr[4];
#pragma unroll
    for (int m = 0; m < 4; ++m)
      af[m] = *(const bf16x8*)&As[(wr * 64 + m * 16 + lr) * 32 + lg * 8];
#pragma unroll
    for (int n = 0; n < 4; ++n)
      bfr[n] = *(const bf16x8*)&Bs[(wc * 64 + n * 16 + lr) * 32 + lg * 8];
#pragma unroll
    for (int m = 0; m < 4; ++m)
#pragma unroll
      for (int n = 0; n < 4; ++n)
        acc[m][n] = __builtin_amdgcn_mfma_f32_16x16x32_bf16(af[m], bfr[n], acc[m][n], 0, 0, 0);
  }
  __syncthreads();  // all As/Bs reads complete before the tile overwrites smem
  const int tg0 = bm * 128;
  if (bn < 20) {
    // per-row sum of squares
#pragma unroll
    for (int m = 0; m < 4; ++m)
#pragma unroll
      for (int r = 0; r < 4; ++r) {
        float ps = 0.f;
#pragma unroll
        for (int n = 0; n < 4; ++n) ps += acc[m][n][r] * acc[m][n][r];
#pragma unroll
        for (int o = 8; o; o >>= 1) ps += __shfl_xor(ps, o);
        if (lr == 0) ssbuf[wr * 64 + m * 16 + lg * 4 + r][wc] = ps;
      }
    // row-major bf16 tile
#pragma unroll
    for (int m = 0; m < 4; ++m)
#pragma unroll
      for (int n = 0; n < 4; ++n)
#pragma unroll
        for (int r = 0; r < 4; ++r)
          smem[(wr * 64 + m * 16 + lg * 4 + r) * 136 + wc * 64 + n * 16 + lr] =
              f2bf(acc[m][n][r]);
    __syncthreads();
    const bool isq = bn < 16;
    const float* nw = isq ? qn_w : kn_w;
    const float qs = isq ? 0.12751744752f : 1.0f;  // 1/(sqrt(128)*ln2) for q
    u16* dstbase = isq ? (qh + (size_t)bn * 2048 * 128)
                       : (kh + (size_t)(bn - 16) * 2048 * 128);
    const int NHl = isq ? 16 : 4;
    for (int it = 0; it < 8; ++it) {
      int idx = it * 256 + tid;        // 0..2047
      int tl = idx >> 4, dg = idx & 15;
      int d0 = dg * 8;
      int tglob = tg0 + tl;
      int tt = tglob & 2047, bb = tglob >> 11;
      float rs = rsqrtf((ssbuf[tl][0] + ssbuf[tl][1]) * (1.0f / 128.0f) + 1e-6f);
      u16x8 a = *(const u16x8*)&smem[tl * 136 + d0];
      u16x8 p = *(const u16x8*)&smem[tl * 136 + (d0 ^ 64)];
      f32x4 c0 = *(const f32x4*)&cosb[tt * 128 + d0];
      f32x4 c1 = *(const f32x4*)&cosb[tt * 128 + d0 + 4];
      f32x4 s0 = *(const f32x4*)&sinb[tt * 128 + d0];
      f32x4 s1 = *(const f32x4*)&sinb[tt * 128 + d0 + 4];
      f32x4 w0 = *(const f32x4*)&nw[d0];
      f32x4 w1 = *(const f32x4*)&nw[d0 + 4];
      f32x4 p0 = *(const f32x4*)&nw[d0 ^ 64];
      f32x4 p1 = *(const f32x4*)&nw[(d0 ^ 64) + 4];
      const float sgn = (d0 < 64) ? -1.0f : 1.0f;
      u16x8 o;
#pragma unroll
      for (int j = 0; j < 8; ++j) {
        float cj = (j < 4) ? c0[j & 3] : c1[j & 3];
        float sj = (j < 4) ? s0[j & 3] : s1[j & 3];
        float wj = (j < 4) ? w0[j & 3] : w1[j & 3];
        float wp = (j < 4) ? p0[j & 3] : p1[j & 3];
        float h1 = bf2f(a[j]) * rs * wj;
        float h2 = bf2f(p[j]) * rs * wp;
        o[j] = f2bf((h1 * cj + sgn * h2 * sj) * qs);
      }
      *(u16x8*)(dstbase + ((size_t)bb * NHl * 2048 + (size_t)tt) * 128 + d0) = o;
    }
  } else {
    // v heads: transposed tile [d][tok], stride 136
#pragma unroll
    for (int m = 0; m < 4; ++m)
#pragma unroll
      for (int n = 0; n < 4; ++n)
#pragma unroll
        for (int r = 0; r < 4; ++r)
          smem[(wc * 64 + n * 16 + lr) * 136 + wr * 64 + m * 16 + lg * 4 + r] =
              f2bf(acc[m][n][r]);
    __syncthreads();
    const int kvi = bn - 20;
    for (int it = 0; it < 8; ++it) {
      int idx = it * 256 + tid;
      int dcol = idx >> 4, tg = idx & 15;
      int tl0 = tg * 8;
      int tglob0 = tg0 + tl0;
      int tt0 = tglob0 & 2047, bb = tglob0 >> 11;
      u16x8 o = *(const u16x8*)&smem[dcol * 136 + tl0];
      *(u16x8*)&vt[((size_t)(bb * 4 + kvi) * 128 + dcol) * 2048 + tt0] = o;
    }
  }
}

// ---------------- bf16 bt-GEMM (m97 structure, 128^2, XCD-localized) for GEMM2 --------
__global__ __launch_bounds__(256) void gemm_bt(
    const u16* __restrict__ A, const u16* __restrict__ B,
    float* __restrict__ C, int M, int N, int K) {
  __shared__ u16 As[128 * 32];
  __shared__ u16 Bs[128 * 32];
  const int tid = threadIdx.x;
  const int lin = blockIdx.x;
  const int x = lin & 7, t = lin >> 3;
  const int bm = x * 4 + (t & 3);
  const int bn = t >> 2;
  const int w = tid >> 6, l = tid & 63;
  const int wr = w >> 1, wc = w & 1;
  const int lr = l & 15, lg = l >> 4;
  f32x4 acc[4][4] = {};
  const int srow = tid >> 2;
  const int scol = (tid & 3) << 3;
  const u16* Ag = A + (size_t)bm * 128 * K + (size_t)srow * K + scol;
  const u16* Bg = B + (size_t)bn * 128 * K + (size_t)srow * K + scol;
  u16* Asl = As + srow * 32 + scol;
  u16* Bsl = Bs + srow * 32 + scol;
  const int nk = K >> 5;
  for (int kt = 0; kt < nk; ++kt) {
    __syncthreads();
    const int ko = kt << 5;
    load_lds16(Ag + ko, Asl);
    load_lds16(Ag + (size_t)64 * K + ko, Asl + 64 * 32);
    load_lds16(Bg + ko, Bsl);
    load_lds16(Bg + (size_t)64 * K + ko, Bsl + 64 * 32);
    __syncthreads();
    bf16x8 af[4], bfr[4];
#pragma unroll
    for (int m = 0; m < 4; ++m)
      af[m] = *(const bf16x8*)&As[(wr * 64 + m * 16 + lr) * 32 + lg * 8];
#pragma unroll
    for (int n = 0; n < 4; ++n)
      bfr[n] = *(const bf16x8*)&Bs[(wc * 64 + n * 16 + lr) * 32 + lg * 8];
#pragma unroll
    for (int m = 0; m < 4; ++m)
#pragma unroll
      for (int n = 0; n < 4; ++n)
        acc[m][n] = __builtin_amdgcn_mfma_f32_16x16x32_bf16(af[m], bfr[n], acc[m][n], 0, 0, 0);
  }
#pragma unroll
  for (int m = 0; m < 4; ++m) {
    const int row = bm * 128 + wr * 64 + m * 16 + lg * 4;
#pragma unroll
    for (int n = 0; n < 4; ++n) {
      const int col = bn * 128 + wc * 64 + n * 16 + lr;
#pragma unroll
      for (int r = 0; r < 4; ++r)
        C[(size_t)(row + r) * N + col] = acc[m][n][r];
    }
  }
}

// ---------------- causal GQA flash attention (R8 verified: 8-warp, log2 softmax) ------
__global__ __launch_bounds__(512, 2) void attn(
    const u16* __restrict__ qhat, const u16* __restrict__ khat,
    const u16* __restrict__ vT, u16* __restrict__ yb) {
  __shared__ u16 Kt[2][64 * 128];
  const int bi = blockIdx.x;           // bh*8 + s
  const int s = bi & 7;
  const int bh = bi >> 3;
  const int h = bh & 15, b = bh >> 4;
  const int kvh = h >> 2;
  const int tid = threadIdx.x;
  const int w = tid >> 6, l = tid & 63;
  const int ws = w & 3;
  const int cw = (w < 4) ? s : (15 - s);
  const int ql = l & 31, hi = l >> 5;
  const int wq0 = cw * 128 + ws * 32;
  const int wq_end = wq0 + 31;
  const int qg = wq0 + ql;

  bf16x8 qf[8];
  const u16* qp = qhat + ((size_t)(b * 16 + h) * 2048 + qg) * 128 + hi * 8;
#pragma unroll
  for (int sf = 0; sf < 8; ++sf) qf[sf] = *(const bf16x8*)(qp + 16 * sf);

  f32x16 yacc[4] = {};
  float m = -1e30f, lsum = 0.f;

  const u16* Kg = khat + (size_t)(b * 4 + kvh) * 2048 * 128;
  const u16* Vg = vT + (size_t)(b * 4 + kvh) * 128 * 2048;
  const int nt = 32 - 2 * s;

  auto stageK = [&](int tile, int buf) {
#pragma unroll
    for (int j = 0; j < 2; ++j) {
      int idx = j * 512 + tid;
      int row = idx >> 4, ch = idx & 15;
      load_lds16(Kg + (size_t)(tile * 64 + row) * 128 + ((ch ^ (row & 7)) * 8),
                 &Kt[buf][idx * 8]);
    }
  };

  stageK(0, 0);
  int cur = 0;
  for (int tile = 0; tile < nt; ++tile) {
    const int kv0 = tile * 64;
    __syncthreads();
    if (tile + 1 < nt) stageK(tile + 1, cur ^ 1);
    if (kv0 <= wq_end) {
      const u16* Vrow = Vg + (size_t)ql * 2048 + kv0 + hi * 8;
      bf16x8 vfr0[4], vfr1[4], vfr2[4], vfr3[4];
#pragma unroll
      for (int ks = 0; ks < 4; ++ks) vfr0[ks] = *(const bf16x8*)(Vrow + ks * 16);
#pragma unroll
      for (int ks = 0; ks < 4; ++ks) vfr1[ks] = *(const bf16x8*)(Vrow + 32 * 2048 + ks * 16);
#pragma unroll
      for (int ks = 0; ks < 4; ++ks) vfr2[ks] = *(const bf16x8*)(Vrow + 64 * 2048 + ks * 16);
#pragma unroll
      for (int ks = 0; ks < 4; ++ks) vfr3[ks] = *(const bf16x8*)(Vrow + 96 * 2048 + ks * 16);
      const u16* Kc = Kt[cur];
      f32x16 sacc[2] = {};
      __builtin_amdgcn_s_setprio(1);
#pragma unroll
      for (int n = 0; n < 2; ++n) {
#pragma unroll
        for (int sf = 0; sf < 8; ++sf) {
          bf16x8 kf = *(const bf16x8*)&Kc[(n * 32 + ql) * 128 + (((2 * sf + hi) ^ (l & 7)) * 8)];
          sacc[n] = __builtin_amdgcn_mfma_f32_32x32x16_bf16(kf, qf[sf], sacc[n], 0, 0, 0);
        }
      }
      __builtin_amdgcn_s_setprio(0);
      if (kv0 + 63 > wq0) {
#pragma unroll
        for (int n = 0; n < 2; ++n)
#pragma unroll
          for (int r = 0; r < 16; ++r) {
            int kv = kv0 + n * 32 + (r & 3) + 8 * (r >> 2) + 4 * hi;
            if (kv > qg) sacc[n][r] = -1e30f;
          }
      }
      float pm = -1e30f;
#pragma unroll
      for (int n = 0; n < 2; ++n)
#pragma unroll
        for (int r = 0; r < 16; ++r) pm = fmaxf(pm, sacc[n][r]);
      pm = fmaxf(pm, __shfl_xor(pm, 32));
      if (!__all(pm - m <= 11.0f)) {
        float mn = fmaxf(m, pm);
        float sc = exp2_fast(m - mn);
        m = mn;
        lsum *= sc;
#pragma unroll
        for (int r = 0; r < 16; ++r) {
          int row = (r & 3) + 8 * (r >> 2) + 4 * hi;
          float scr = __shfl(sc, row);
#pragma unroll
          for (int d = 0; d < 4; ++d) yacc[d][r] *= scr;
        }
      }
      float ls = 0.f;
#pragma unroll
      for (int n = 0; n < 2; ++n)
#pragma unroll
        for (int r = 0; r < 16; ++r) {
          float e = exp2_fast(sacc[n][r] - m);
          sacc[n][r] = e;
          ls += e;
        }
      ls += __shfl_xor(ls, 32);
      lsum += ls;
      bf16x8 pa[4];
#pragma unroll
      for (int s4 = 0; s4 < 4; ++s4) {
        const int n = s4 >> 1, R = (s4 & 1) * 8;
        unsigned P01 = cvtpk(sacc[n][R + 0], sacc[n][R + 1]);
        unsigned P23 = cvtpk(sacc[n][R + 2], sacc[n][R + 3]);
        unsigned P45 = cvtpk(sacc[n][R + 4], sacc[n][R + 5]);
        unsigned P67 = cvtpk(sacc[n][R + 6], sacc[n][R + 7]);
        plane32_swap(P01, P45);
        plane32_swap(P23, P67);
        union { u32x4 u; bf16x8 bv; } cvu;
        cvu.u[0] = P01; cvu.u[1] = P23; cvu.u[2] = P45; cvu.u[3] = P67;
        pa[s4] = cvu.bv;
      }
      __builtin_amdgcn_s_setprio(1);
#pragma unroll
      for (int ks = 0; ks < 4; ++ks) {
        yacc[0] = __builtin_amdgcn_mfma_f32_32x32x16_bf16(pa[ks], vfr0[ks], yacc[0], 0, 0, 0);
        yacc[1] = __builtin_amdgcn_mfma_f32_32x32x16_bf16(pa[ks], vfr1[ks], yacc[1], 0, 0, 0);
        yacc[2] = __builtin_amdgcn_mfma_f32_32x32x16_bf16(pa[ks], vfr2[ks], yacc[2], 0, 0, 0);
        yacc[3] = __builtin_amdgcn_mfma_f32_32x32x16_bf16(pa[ks], vfr3[ks], yacc[3], 0, 0, 0);
      }
      __builtin_amdgcn_s_setprio(0);
    }
    cur ^= 1;
  }
#pragma unroll
  for (int r = 0; r < 16; ++r) {
    int row = (r & 3) + 8 * (r >> 2) + 4 * hi;
    float li = __shfl(lsum, row);
    float inv = 1.0f / li;
    u16* yp = yb + ((size_t)(b * 2048) + wq0 + row) * 2048 + h * 128 + ql;
#pragma unroll
    for (int d = 0; d < 4; ++d) yp[d * 32] = f2bf(yacc[d][r] * inv);
  }
}

// ---------------- launcher ----------------

extern "C" void kernel_launch(void* const* d_in, const int* in_sizes, int n_in,
                              void* d_out, int out_size, void* d_ws, size_t ws_size,
                              hipStream_t stream) {
  const float* x    = (const float*)d_in[0];
  const float* Wq   = (const float*)d_in[1];
  const float* Wk   = (const float*)d_in[2];
  const float* Wv   = (const float*)d_in[3];
  const float* Wo   = (const float*)d_in[4];
  const float* qn   = (const float*)d_in[5];
  const float* kn   = (const float*)d_in[6];
  const float* cosb = (const float*)d_in[7];
  const float* sinb = (const float*)d_in[8];
  float* out = (float*)d_out;
  (void)in_sizes; (void)n_in; (void)out_size; (void)ws_size;

  char* p = (char*)d_ws;
  u16*   xb   = (u16*)p;   p += (size_t)8388608 * 2;    // x bf16 [4096,2048]
  u16*   wcat = (u16*)p;   p += (size_t)6291456 * 2;    // [3072,2048]
  u16*   wob  = (u16*)p;   p += (size_t)4194304 * 2;    // [2048,2048]
  u16*   qh   = (u16*)p;   p += (size_t)8388608 * 2;    // [2,16,2048,128]
  u16*   kh   = (u16*)p;   p += (size_t)2097152 * 2;    // [2,4,2048,128]
  u16*   vt   = (u16*)p;   p += (size_t)2097152 * 2;    // [2,4,128,2048]
  u16*   yb   = (u16*)p;   p += (size_t)8388608 * 2;    // [4096,2048]

  cvt_f32_bf16<<<2048, 256, 0, stream>>>(x, xb, 8388608);
  build_wcat<<<2048, 256, 0, stream>>>(Wq, Wk, Wv, wcat);
  cvt_f32_bf16<<<2048, 256, 0, stream>>>(Wo, wob, 4194304);
  gemm_qkv<<<768, 256, 0, stream>>>(xb, wcat, qn, kn, cosb, sinb, qh, kh, vt);
  attn<<<256, 512, 0, stream>>>(qh, kh, vt, yb);
  gemm_bt<<<512, 256, 0, stream>>>(yb, wob, out, 4096, 2048, 2048);
}

// Round 12
// 242.067 us; speedup vs baseline: 1.1977x; 1.1977x over previous
//
#include <hip/hip_runtime.h>
#include <stdint.h>

typedef unsigned short u16;
typedef __attribute__((ext_vector_type(4))) float f32x4;
typedef __attribute__((ext_vector_type(16))) float f32x16;
typedef __attribute__((ext_vector_type(8))) short bf16x8;
typedef __attribute__((ext_vector_type(4))) unsigned short u16x4;
typedef __attribute__((ext_vector_type(4))) unsigned u32x4;

static __device__ __forceinline__ u16 f2bf(float f) {
  union { float f; unsigned u; } v; v.f = f;
  unsigned r = v.u + 0x7fffu + ((v.u >> 16) & 1u);
  return (u16)(r >> 16);
}

static __device__ __forceinline__ unsigned cvtpk(float lo, float hi) {
  unsigned r;
  asm("v_cvt_pk_bf16_f32 %0, %1, %2" : "=v"(r) : "v"(lo), "v"(hi));
  return r;
}

static __device__ __forceinline__ void plane32_swap(unsigned& a, unsigned& b) {
  asm volatile("v_permlane32_swap_b32 %0, %1" : "+v"(a), "+v"(b));
}

static __device__ __forceinline__ float exp2_fast(float x) {
  float r;
  asm("v_exp_f32 %0, %1" : "=v"(r) : "v"(x));
  return r;
}

static __device__ __forceinline__ void load_lds16(const void* g, void* l) {
  __builtin_amdgcn_global_load_lds(
      (const __attribute__((address_space(1))) void*)g,
      (__attribute__((address_space(3))) void*)l, 16, 0, 0);
}

// ---------------- conversion kernels ----------------

__global__ __launch_bounds__(256) void cvt_f32_bf16(
    const float* __restrict__ in, u16* __restrict__ out, int n) {
  int i = blockIdx.x * 256 + threadIdx.x;
  const int n4 = n >> 2;
  for (; i < n4; i += gridDim.x * 256) {
    f32x4 v = *(const f32x4*)(in + (size_t)i * 4);
    u16x4 o = { f2bf(v[0]), f2bf(v[1]), f2bf(v[2]), f2bf(v[3]) };
    *(u16x4*)(out + (size_t)i * 4) = o;
  }
}

__global__ __launch_bounds__(256) void build_wcat(
    const float* __restrict__ Wq, const float* __restrict__ Wk,
    const float* __restrict__ Wv, u16* __restrict__ out) {
  int i = blockIdx.x * 256 + threadIdx.x;
  const int n4 = 3072 * 512;
  for (; i < n4; i += gridDim.x * 256) {
    int row = i >> 9;
    int c4 = i & 511;
    const float* src;
    if (row < 2048)       src = Wq + (size_t)row * 2048;
    else if (row < 2560)  src = Wk + (size_t)(row - 2048) * 2048;
    else                  src = Wv + (size_t)(row - 2560) * 2048;
    f32x4 v = *(const f32x4*)(src + c4 * 4);
    u16x4 o = { f2bf(v[0]), f2bf(v[1]), f2bf(v[2]), f2bf(v[3]) };
    *(u16x4*)(out + (size_t)i * 4) = o;
  }
}

// ---------------- bf16 bt-GEMM (m97 structure, 128^2, XCD-localized): C = A B^T -------
__global__ __launch_bounds__(256) void gemm_bt(
    const u16* __restrict__ A, const u16* __restrict__ B,
    float* __restrict__ C, int M, int N, int K) {
  __shared__ u16 As[128 * 32];
  __shared__ u16 Bs[128 * 32];
  const int tid = threadIdx.x;
  const int lin = blockIdx.x;
  const int x = lin & 7, t = lin >> 3;   // bid%8 == XCD (round-robin dispatch)
  const int bm = x * 4 + (t & 3);
  const int bn = t >> 2;
  const int w = tid >> 6, l = tid & 63;
  const int wr = w >> 1, wc = w & 1;
  const int lr = l & 15, lg = l >> 4;
  f32x4 acc[4][4] = {};
  const int srow = tid >> 2;
  const int scol = (tid & 3) << 3;
  const u16* Ag = A + (size_t)bm * 128 * K + (size_t)srow * K + scol;
  const u16* Bg = B + (size_t)bn * 128 * K + (size_t)srow * K + scol;
  u16* Asl = As + srow * 32 + scol;
  u16* Bsl = Bs + srow * 32 + scol;
  const int nk = K >> 5;
  for (int kt = 0; kt < nk; ++kt) {
    __syncthreads();
    const int ko = kt << 5;
    load_lds16(Ag + ko, Asl);
    load_lds16(Ag + (size_t)64 * K + ko, Asl + 64 * 32);
    load_lds16(Bg + ko, Bsl);
    load_lds16(Bg + (size_t)64 * K + ko, Bsl + 64 * 32);
    __syncthreads();
    bf16x8 af[4], bfr[4];
#pragma unroll
    for (int m = 0; m < 4; ++m)
      af[m] = *(const bf16x8*)&As[(wr * 64 + m * 16 + lr) * 32 + lg * 8];
#pragma unroll
    for (int n = 0; n < 4; ++n)
      bfr[n] = *(const bf16x8*)&Bs[(wc * 64 + n * 16 + lr) * 32 + lg * 8];
#pragma unroll
    for (int m = 0; m < 4; ++m)
#pragma unroll
      for (int n = 0; n < 4; ++n)
        acc[m][n] = __builtin_amdgcn_mfma_f32_16x16x32_bf16(af[m], bfr[n], acc[m][n], 0, 0, 0);
  }
#pragma unroll
  for (int m = 0; m < 4; ++m) {
    const int row = bm * 128 + wr * 64 + m * 16 + lg * 4;
#pragma unroll
    for (int n = 0; n < 4; ++n) {
      const int col = bn * 128 + wc * 64 + n * 16 + lr;
#pragma unroll
      for (int r = 0; r < 4; ++r)
        C[(size_t)(row + r) * N + col] = acc[m][n][r];
    }
  }
}

// ---------------- per-head RMSNorm + RoPE (q scaled by 1/(sqrt(128)*ln2)) -------------
__global__ __launch_bounds__(256) void norm_rope(
    const float* __restrict__ qkv, const float* __restrict__ qn_w,
    const float* __restrict__ kn_w, const float* __restrict__ cosb,
    const float* __restrict__ sinb, u16* __restrict__ qhat,
    u16* __restrict__ khat) {
  const int gw = (blockIdx.x * 256 + threadIdx.x) >> 6;
  const int lane = threadIdx.x & 63;
  const int slot = gw % 20;
  const int row = gw / 20;  // b*2048 + t
  const int t = row & 2047;
  const int b = row >> 11;
  const float* src; const float* nw; u16* dst;
  bool isq = slot < 16;
  if (isq) {
    src = qkv + (size_t)row * 3072 + slot * 128;
    nw = qn_w;
    dst = qhat + ((size_t)(b * 16 + slot) * 2048 + t) * 128;
  } else {
    src = qkv + (size_t)row * 3072 + 2048 + (slot - 16) * 128;
    nw = kn_w;
    dst = khat + ((size_t)(b * 4 + (slot - 16)) * 2048 + t) * 128;
  }
  float x1 = src[lane], x2 = src[lane + 64];
  float ss = x1 * x1 + x2 * x2;
#pragma unroll
  for (int o = 32; o; o >>= 1) ss += __shfl_xor(ss, o);
  float rs = rsqrtf(ss * (1.0f / 128.0f) + 1e-6f);
  float h1 = x1 * rs * nw[lane];
  float h2 = x2 * rs * nw[lane + 64];
  float c = cosb[t * 128 + lane], s = sinb[t * 128 + lane];
  float o1 = h1 * c - h2 * s;
  float o2 = h2 * c + h1 * s;
  if (isq) { o1 *= 0.12751744752f; o2 *= 0.12751744752f; }  // 1/(sqrt(128)*ln2)
  dst[lane] = f2bf(o1);
  dst[lane + 64] = f2bf(o2);
}

// ---------------- V transpose: qkv fp32 [.,3072] v-cols -> vT bf16 [B,KV,D,T] ---------
__global__ __launch_bounds__(256) void v_trans(
    const float* __restrict__ qkv, u16* __restrict__ vT) {
  __shared__ u16 st[64][130];
  const int bi = blockIdx.x;
  const int tt = bi & 31;
  const int kv = (bi >> 5) & 3;
  const int b = bi >> 7;
  const int tid = threadIdx.x;
#pragma unroll
  for (int i = 0; i < 32; ++i) {
    int idx = i * 256 + tid;
    int t = idx >> 7, d = idx & 127;
    float v = qkv[(size_t)(b * 2048 + tt * 64 + t) * 3072 + 2560 + kv * 128 + d];
    st[t][d] = f2bf(v);
  }
  __syncthreads();
#pragma unroll
  for (int i = 0; i < 32; ++i) {
    int idx = i * 256 + tid;
    int d = idx >> 6, t = idx & 63;
    vT[((size_t)(b * 4 + kv) * 128 + d) * 2048 + tt * 64 + t] = st[t][d];
  }
}

// ---------------- causal GQA flash attention (8-warp, V staged in LDS) ----------------
// Theory (R11 post-mortem): direct-global V fragments are 4KB-strided per lane -> every
// V load = ~64 cache transactions; 16/tile/warp = ~1k serialized VMEM transactions that
// pinned attn at ~99us across R4/R6/R8. Now V tiles staged to LDS like K (global side
// is coalesced 128B row-runs; pre-swizzled src + linear dest + swizzled ds_read).
__global__ __launch_bounds__(512, 2) void attn(
    const u16* __restrict__ qhat, const u16* __restrict__ khat,
    const u16* __restrict__ vT, u16* __restrict__ yb) {
  __shared__ u16 Kt[2][64 * 128];   // 32 KB
  __shared__ u16 Vt[2][128 * 64];   // 32 KB  (rows = d 0..127, cols = 64 kv)
  const int bi = blockIdx.x;        // bh*8 + s
  const int s = bi & 7;
  const int bh = bi >> 3;
  const int h = bh & 15, b = bh >> 4;
  const int kvh = h >> 2;
  const int tid = threadIdx.x;
  const int w = tid >> 6, l = tid & 63;
  const int ws = w & 3;
  const int cw = (w < 4) ? s : (15 - s);
  const int ql = l & 31, hi = l >> 5;
  const int wq0 = cw * 128 + ws * 32;
  const int wq_end = wq0 + 31;
  const int qg = wq0 + ql;

  bf16x8 qf[8];
  const u16* qp = qhat + ((size_t)(b * 16 + h) * 2048 + qg) * 128 + hi * 8;
#pragma unroll
  for (int sf = 0; sf < 8; ++sf) qf[sf] = *(const bf16x8*)(qp + 16 * sf);

  f32x16 yacc[4] = {};
  float m = -1e30f, lsum = 0.f;

  const u16* Kg = khat + (size_t)(b * 4 + kvh) * 2048 * 128;
  const u16* Vg = vT + (size_t)(b * 4 + kvh) * 128 * 2048;
  const int nt = 32 - 2 * s;

  // K tile: 64 rows x 128 d; 1024 chunks of 16B; pre-swizzled src, linear dest
  auto stageK = [&](int tile, int buf) {
#pragma unroll
    for (int j = 0; j < 2; ++j) {
      int idx = j * 512 + tid;
      int row = idx >> 4, ch = idx & 15;
      load_lds16(Kg + (size_t)(tile * 64 + row) * 128 + ((ch ^ (row & 7)) * 8),
                 &Kt[buf][idx * 8]);
    }
  };
  // V tile: 128 rows (d) x 64 kv; 1024 chunks of 16B (8 per row); coalesced 128B runs
  auto stageV = [&](int tile, int buf) {
#pragma unroll
    for (int j = 0; j < 2; ++j) {
      int idx = j * 512 + tid;
      int row = idx >> 3, ch = idx & 7;
      load_lds16(Vg + (size_t)row * 2048 + tile * 64 + ((ch ^ (row & 7)) * 8),
                 &Vt[buf][idx * 8]);
    }
  };

  stageK(0, 0);
  stageV(0, 0);
  int cur = 0;
  for (int tile = 0; tile < nt; ++tile) {
    const int kv0 = tile * 64;
    __syncthreads();  // implicit vmcnt drain: Kt/Vt[cur] ready & visible
    if (tile + 1 < nt) { stageK(tile + 1, cur ^ 1); stageV(tile + 1, cur ^ 1); }
    if (kv0 <= wq_end) {
      const u16* Kc = Kt[cur];
      const u16* Vc = Vt[cur];
      f32x16 sacc[2] = {};
      __builtin_amdgcn_s_setprio(1);
#pragma unroll
      for (int n = 0; n < 2; ++n) {
#pragma unroll
        for (int sf = 0; sf < 8; ++sf) {
          bf16x8 kf = *(const bf16x8*)&Kc[(n * 32 + ql) * 128 + (((2 * sf + hi) ^ (l & 7)) * 8)];
          sacc[n] = __builtin_amdgcn_mfma_f32_32x32x16_bf16(kf, qf[sf], sacc[n], 0, 0, 0);
        }
      }
      __builtin_amdgcn_s_setprio(0);
      if (kv0 + 63 > wq0) {
#pragma unroll
        for (int n = 0; n < 2; ++n)
#pragma unroll
          for (int r = 0; r < 16; ++r) {
            int kv = kv0 + n * 32 + (r & 3) + 8 * (r >> 2) + 4 * hi;
            if (kv > qg) sacc[n][r] = -1e30f;
          }
      }
      float pm = -1e30f;
#pragma unroll
      for (int n = 0; n < 2; ++n)
#pragma unroll
        for (int r = 0; r < 16; ++r) pm = fmaxf(pm, sacc[n][r]);
      pm = fmaxf(pm, __shfl_xor(pm, 32));
      if (!__all(pm - m <= 11.0f)) {  // defer-max, log2 units (P <= 2^11)
        float mn = fmaxf(m, pm);
        float sc = exp2_fast(m - mn);
        m = mn;
        lsum *= sc;
#pragma unroll
        for (int r = 0; r < 16; ++r) {
          int row = (r & 3) + 8 * (r >> 2) + 4 * hi;
          float scr = __shfl(sc, row);
#pragma unroll
          for (int d = 0; d < 4; ++d) yacc[d][r] *= scr;
        }
      }
      float ls = 0.f;
#pragma unroll
      for (int n = 0; n < 2; ++n)
#pragma unroll
        for (int r = 0; r < 16; ++r) {
          float e = exp2_fast(sacc[n][r] - m);
          sacc[n][r] = e;
          ls += e;
        }
      ls += __shfl_xor(ls, 32);
      lsum += ls;
      bf16x8 pa[4];
#pragma unroll
      for (int s4 = 0; s4 < 4; ++s4) {
        const int n = s4 >> 1, R = (s4 & 1) * 8;
        unsigned P01 = cvtpk(sacc[n][R + 0], sacc[n][R + 1]);
        unsigned P23 = cvtpk(sacc[n][R + 2], sacc[n][R + 3]);
        unsigned P45 = cvtpk(sacc[n][R + 4], sacc[n][R + 5]);
        unsigned P67 = cvtpk(sacc[n][R + 6], sacc[n][R + 7]);
        plane32_swap(P01, P45);
        plane32_swap(P23, P67);
        union { u32x4 u; bf16x8 bv; } cvu;
        cvu.u[0] = P01; cvu.u[1] = P23; cvu.u[2] = P45; cvu.u[3] = P67;
        pa[s4] = cvu.bv;
      }
      // PV: V fragments from LDS (swizzled ds_read_b128)
      __builtin_amdgcn_s_setprio(1);
#pragma unroll
      for (int d = 0; d < 4; ++d) {
        const int rv = d * 32 + ql;
#pragma unroll
        for (int ks = 0; ks < 4; ++ks) {
          bf16x8 vf = *(const bf16x8*)&Vc[rv * 64 + (((ks * 2 + hi) ^ (rv & 7)) * 8)];
          yacc[d] = __builtin_amdgcn_mfma_f32_32x32x16_bf16(pa[ks], vf, yacc[d], 0, 0, 0);
        }
      }
      __builtin_amdgcn_s_setprio(0);
    }
    cur ^= 1;
  }
#pragma unroll
  for (int r = 0; r < 16; ++r) {
    int row = (r & 3) + 8 * (r >> 2) + 4 * hi;
    float li = __shfl(lsum, row);
    float inv = 1.0f / li;
    u16* yp = yb + ((size_t)(b * 2048) + wq0 + row) * 2048 + h * 128 + ql;
#pragma unroll
    for (int d = 0; d < 4; ++d) yp[d * 32] = f2bf(yacc[d][r] * inv);
  }
}

// ---------------- launcher ----------------

extern "C" void kernel_launch(void* const* d_in, const int* in_sizes, int n_in,
                              void* d_out, int out_size, void* d_ws, size_t ws_size,
                              hipStream_t stream) {
  const float* x    = (const float*)d_in[0];
  const float* Wq   = (const float*)d_in[1];
  const float* Wk   = (const float*)d_in[2];
  const float* Wv   = (const float*)d_in[3];
  const float* Wo   = (const float*)d_in[4];
  const float* qn   = (const float*)d_in[5];
  const float* kn   = (const float*)d_in[6];
  const float* cosb = (const float*)d_in[7];
  const float* sinb = (const float*)d_in[8];
  float* out = (float*)d_out;
  (void)in_sizes; (void)n_in; (void)out_size; (void)ws_size;

  char* p = (char*)d_ws;
  u16*   xb   = (u16*)p;   p += (size_t)8388608 * 2;    // x bf16 [4096,2048]
  u16*   wcat = (u16*)p;   p += (size_t)6291456 * 2;    // [3072,2048]
  u16*   wob  = (u16*)p;   p += (size_t)4194304 * 2;    // [2048,2048]
  float* qkvf = (float*)p; p += (size_t)12582912 * 4;   // [4096,3072] fp32
  u16*   qh   = (u16*)p;   p += (size_t)8388608 * 2;    // [2,16,2048,128]
  u16*   kh   = (u16*)p;   p += (size_t)2097152 * 2;    // [2,4,2048,128]
  u16*   vt   = (u16*)p;   p += (size_t)2097152 * 2;    // [2,4,128,2048]
  u16*   yb   = (u16*)p;   p += (size_t)8388608 * 2;    // [4096,2048]

  cvt_f32_bf16<<<2048, 256, 0, stream>>>(x, xb, 8388608);
  build_wcat<<<2048, 256, 0, stream>>>(Wq, Wk, Wv, wcat);
  cvt_f32_bf16<<<2048, 256, 0, stream>>>(Wo, wob, 4194304);
  gemm_bt<<<768, 256, 0, stream>>>(xb, wcat, qkvf, 4096, 3072, 2048);
  norm_rope<<<20480, 256, 0, stream>>>(qkvf, qn, kn, cosb, sinb, qh, kh);
  v_trans<<<256, 256, 0, stream>>>(qkvf, vt);
  attn<<<256, 512, 0, stream>>>(qh, kh, vt, yb);
  gemm_bt<<<512, 256, 0, stream>>>(yb, wob, out, 4096, 2048, 2048);
}

// Round 13
// 238.182 us; speedup vs baseline: 1.2172x; 1.0163x over previous
//
#include <hip/hip_runtime.h>
#include <stdint.h>

typedef unsigned short u16;
typedef __attribute__((ext_vector_type(4))) float f32x4;
typedef __attribute__((ext_vector_type(16))) float f32x16;
typedef __attribute__((ext_vector_type(8))) short bf16x8;
typedef __attribute__((ext_vector_type(4))) unsigned short u16x4;
typedef __attribute__((ext_vector_type(4))) unsigned u32x4;

static __device__ __forceinline__ u16 f2bf(float f) {
  union { float f; unsigned u; } v; v.f = f;
  unsigned r = v.u + 0x7fffu + ((v.u >> 16) & 1u);
  return (u16)(r >> 16);
}

static __device__ __forceinline__ unsigned cvtpk(float lo, float hi) {
  unsigned r;
  asm("v_cvt_pk_bf16_f32 %0, %1, %2" : "=v"(r) : "v"(lo), "v"(hi));
  return r;
}

static __device__ __forceinline__ void plane32_swap(unsigned& a, unsigned& b) {
  asm volatile("v_permlane32_swap_b32 %0, %1" : "+v"(a), "+v"(b));
}

static __device__ __forceinline__ float exp2_fast(float x) {
  float r;
  asm("v_exp_f32 %0, %1" : "=v"(r) : "v"(x));
  return r;
}

static __device__ __forceinline__ void load_lds16(const void* g, void* l) {
  __builtin_amdgcn_global_load_lds(
      (const __attribute__((address_space(1))) void*)g,
      (__attribute__((address_space(3))) void*)l, 16, 0, 0);
}

// ---------------- conversion kernels ----------------

__global__ __launch_bounds__(256) void cvt_f32_bf16(
    const float* __restrict__ in, u16* __restrict__ out, int n) {
  int i = blockIdx.x * 256 + threadIdx.x;
  const int n4 = n >> 2;
  for (; i < n4; i += gridDim.x * 256) {
    f32x4 v = *(const f32x4*)(in + (size_t)i * 4);
    u16x4 o = { f2bf(v[0]), f2bf(v[1]), f2bf(v[2]), f2bf(v[3]) };
    *(u16x4*)(out + (size_t)i * 4) = o;
  }
}

__global__ __launch_bounds__(256) void build_wcat(
    const float* __restrict__ Wq, const float* __restrict__ Wk,
    const float* __restrict__ Wv, u16* __restrict__ out) {
  int i = blockIdx.x * 256 + threadIdx.x;
  const int n4 = 3072 * 512;
  for (; i < n4; i += gridDim.x * 256) {
    int row = i >> 9;
    int c4 = i & 511;
    const float* src;
    if (row < 2048)       src = Wq + (size_t)row * 2048;
    else if (row < 2560)  src = Wk + (size_t)(row - 2048) * 2048;
    else                  src = Wv + (size_t)(row - 2560) * 2048;
    f32x4 v = *(const f32x4*)(src + c4 * 4);
    u16x4 o = { f2bf(v[0]), f2bf(v[1]), f2bf(v[2]), f2bf(v[3]) };
    *(u16x4*)(out + (size_t)i * 4) = o;
  }
}

// ---------------- bf16 bt-GEMM (m97 staging, 32x32x16 MFMA core): C = A B^T ----------
// Wave tile 64x64 as 2x2 of 32x32 -> 8 MFMA/kt (was 16 of 16x16x32): ~15% fewer matrix
// cycles (m119) + half the MFMA issue slots (VALUBusy was 48%). Fragment reads span 32
// rows at a fixed 16B chunk -> swizzle chunk c ^= (row&3): staging keeps linear LDS dest
// (global_load_lds constraint) and pre-swizzles the GLOBAL source chunk; reads XOR the
// same involution. Bank map: uniform 8 dwords/bank (conflict-free). XCD-localized bm.
__global__ __launch_bounds__(256) void gemm_bt(
    const u16* __restrict__ A, const u16* __restrict__ B,
    float* __restrict__ C, int M, int N, int K) {
  __shared__ u16 As[128 * 32];
  __shared__ u16 Bs[128 * 32];
  const int tid = threadIdx.x;
  const int lin = blockIdx.x;
  const int x = lin & 7, t = lin >> 3;   // bid%8 == XCD (round-robin dispatch)
  const int bm = x * 4 + (t & 3);
  const int bn = t >> 2;
  const int w = tid >> 6, l = tid & 63;
  const int wr = w >> 1, wc = w & 1;
  const int ql = l & 31, hi = l >> 5;
  f32x16 acc[2][2] = {};
  const int srow = tid >> 2;
  const int scol = (((tid & 3) ^ (srow & 3)) << 3);  // pre-swizzled source chunk
  const u16* Ag = A + (size_t)bm * 128 * K + (size_t)srow * K + scol;
  const u16* Bg = B + (size_t)bn * 128 * K + (size_t)srow * K + scol;
  u16* Asl = As + tid * 8;               // linear dest (tid*16B)
  u16* Bsl = Bs + tid * 8;
  const int nk = K >> 5;
  for (int kt = 0; kt < nk; ++kt) {
    __syncthreads();
    const int ko = kt << 5;
    load_lds16(Ag + ko, Asl);
    load_lds16(Ag + (size_t)64 * K + ko, Asl + 64 * 32);
    load_lds16(Bg + ko, Bsl);
    load_lds16(Bg + (size_t)64 * K + ko, Bsl + 64 * 32);
    __syncthreads();
#pragma unroll
    for (int ks = 0; ks < 2; ++ks) {
      const int e = ks * 2 + hi;
      bf16x8 af[2], bfr[2];
#pragma unroll
      for (int ti = 0; ti < 2; ++ti) {
        const int ra = wr * 64 + ti * 32 + ql;
        const int rb = wc * 64 + ti * 32 + ql;
        af[ti]  = *(const bf16x8*)&As[ra * 32 + ((e ^ (ra & 3)) << 3)];
        bfr[ti] = *(const bf16x8*)&Bs[rb * 32 + ((e ^ (rb & 3)) << 3)];
      }
#pragma unroll
      for (int mi = 0; mi < 2; ++mi)
#pragma unroll
        for (int ni = 0; ni < 2; ++ni)
          acc[mi][ni] = __builtin_amdgcn_mfma_f32_32x32x16_bf16(
              af[mi], bfr[ni], acc[mi][ni], 0, 0, 0);
    }
  }
  // epilogue: C/D layout col=ql, row=(r&3)+8*(r>>2)+4*hi
#pragma unroll
  for (int mi = 0; mi < 2; ++mi) {
    const int rb0 = bm * 128 + wr * 64 + mi * 32;
#pragma unroll
    for (int ni = 0; ni < 2; ++ni) {
      const int col = bn * 128 + wc * 64 + ni * 32 + ql;
#pragma unroll
      for (int r = 0; r < 16; ++r) {
        const int row = rb0 + (r & 3) + 8 * (r >> 2) + 4 * hi;
        C[(size_t)row * N + col] = acc[mi][ni][r];
      }
    }
  }
}

// ---------------- per-head RMSNorm + RoPE (q scaled by 1/(sqrt(128)*ln2)) -------------
__global__ __launch_bounds__(256) void norm_rope(
    const float* __restrict__ qkv, const float* __restrict__ qn_w,
    const float* __restrict__ kn_w, const float* __restrict__ cosb,
    const float* __restrict__ sinb, u16* __restrict__ qhat,
    u16* __restrict__ khat) {
  const int gw = (blockIdx.x * 256 + threadIdx.x) >> 6;
  const int lane = threadIdx.x & 63;
  const int slot = gw % 20;
  const int row = gw / 20;  // b*2048 + t
  const int t = row & 2047;
  const int b = row >> 11;
  const float* src; const float* nw; u16* dst;
  bool isq = slot < 16;
  if (isq) {
    src = qkv + (size_t)row * 3072 + slot * 128;
    nw = qn_w;
    dst = qhat + ((size_t)(b * 16 + slot) * 2048 + t) * 128;
  } else {
    src = qkv + (size_t)row * 3072 + 2048 + (slot - 16) * 128;
    nw = kn_w;
    dst = khat + ((size_t)(b * 4 + (slot - 16)) * 2048 + t) * 128;
  }
  float x1 = src[lane], x2 = src[lane + 64];
  float ss = x1 * x1 + x2 * x2;
#pragma unroll
  for (int o = 32; o; o >>= 1) ss += __shfl_xor(ss, o);
  float rs = rsqrtf(ss * (1.0f / 128.0f) + 1e-6f);
  float h1 = x1 * rs * nw[lane];
  float h2 = x2 * rs * nw[lane + 64];
  float c = cosb[t * 128 + lane], s = sinb[t * 128 + lane];
  float o1 = h1 * c - h2 * s;
  float o2 = h2 * c + h1 * s;
  if (isq) { o1 *= 0.12751744752f; o2 *= 0.12751744752f; }  // 1/(sqrt(128)*ln2)
  dst[lane] = f2bf(o1);
  dst[lane + 64] = f2bf(o2);
}

// ---------------- V transpose: qkv fp32 [.,3072] v-cols -> vT bf16 [B,KV,D,T] ---------
__global__ __launch_bounds__(256) void v_trans(
    const float* __restrict__ qkv, u16* __restrict__ vT) {
  __shared__ u16 st[64][130];
  const int bi = blockIdx.x;
  const int tt = bi & 31;
  const int kv = (bi >> 5) & 3;
  const int b = bi >> 7;
  const int tid = threadIdx.x;
#pragma unroll
  for (int i = 0; i < 32; ++i) {
    int idx = i * 256 + tid;
    int t = idx >> 7, d = idx & 127;
    float v = qkv[(size_t)(b * 2048 + tt * 64 + t) * 3072 + 2560 + kv * 128 + d];
    st[t][d] = f2bf(v);
  }
  __syncthreads();
#pragma unroll
  for (int i = 0; i < 32; ++i) {
    int idx = i * 256 + tid;
    int d = idx >> 6, t = idx & 63;
    vT[((size_t)(b * 4 + kv) * 128 + d) * 2048 + tt * 64 + t] = st[t][d];
  }
}

// ---------------- causal GQA flash attention (R12 verified: 8-warp, K+V in LDS) -------
__global__ __launch_bounds__(512, 2) void attn(
    const u16* __restrict__ qhat, const u16* __restrict__ khat,
    const u16* __restrict__ vT, u16* __restrict__ yb) {
  __shared__ u16 Kt[2][64 * 128];   // 32 KB
  __shared__ u16 Vt[2][128 * 64];   // 32 KB  (rows = d 0..127, cols = 64 kv)
  const int bi = blockIdx.x;        // bh*8 + s
  const int s = bi & 7;
  const int bh = bi >> 3;
  const int h = bh & 15, b = bh >> 4;
  const int kvh = h >> 2;
  const int tid = threadIdx.x;
  const int w = tid >> 6, l = tid & 63;
  const int ws = w & 3;
  const int cw = (w < 4) ? s : (15 - s);
  const int ql = l & 31, hi = l >> 5;
  const int wq0 = cw * 128 + ws * 32;
  const int wq_end = wq0 + 31;
  const int qg = wq0 + ql;

  bf16x8 qf[8];
  const u16* qp = qhat + ((size_t)(b * 16 + h) * 2048 + qg) * 128 + hi * 8;
#pragma unroll
  for (int sf = 0; sf < 8; ++sf) qf[sf] = *(const bf16x8*)(qp + 16 * sf);

  f32x16 yacc[4] = {};
  float m = -1e30f, lsum = 0.f;

  const u16* Kg = khat + (size_t)(b * 4 + kvh) * 2048 * 128;
  const u16* Vg = vT + (size_t)(b * 4 + kvh) * 128 * 2048;
  const int nt = 32 - 2 * s;

  auto stageK = [&](int tile, int buf) {
#pragma unroll
    for (int j = 0; j < 2; ++j) {
      int idx = j * 512 + tid;
      int row = idx >> 4, ch = idx & 15;
      load_lds16(Kg + (size_t)(tile * 64 + row) * 128 + ((ch ^ (row & 7)) * 8),
                 &Kt[buf][idx * 8]);
    }
  };
  auto stageV = [&](int tile, int buf) {
#pragma unroll
    for (int j = 0; j < 2; ++j) {
      int idx = j * 512 + tid;
      int row = idx >> 3, ch = idx & 7;
      load_lds16(Vg + (size_t)row * 2048 + tile * 64 + ((ch ^ (row & 7)) * 8),
                 &Vt[buf][idx * 8]);
    }
  };

  stageK(0, 0);
  stageV(0, 0);
  int cur = 0;
  for (int tile = 0; tile < nt; ++tile) {
    const int kv0 = tile * 64;
    __syncthreads();
    if (tile + 1 < nt) { stageK(tile + 1, cur ^ 1); stageV(tile + 1, cur ^ 1); }
    if (kv0 <= wq_end) {
      const u16* Kc = Kt[cur];
      const u16* Vc = Vt[cur];
      f32x16 sacc[2] = {};
      __builtin_amdgcn_s_setprio(1);
#pragma unroll
      for (int n = 0; n < 2; ++n) {
#pragma unroll
        for (int sf = 0; sf < 8; ++sf) {
          bf16x8 kf = *(const bf16x8*)&Kc[(n * 32 + ql) * 128 + (((2 * sf + hi) ^ (l & 7)) * 8)];
          sacc[n] = __builtin_amdgcn_mfma_f32_32x32x16_bf16(kf, qf[sf], sacc[n], 0, 0, 0);
        }
      }
      __builtin_amdgcn_s_setprio(0);
      if (kv0 + 63 > wq0) {
#pragma unroll
        for (int n = 0; n < 2; ++n)
#pragma unroll
          for (int r = 0; r < 16; ++r) {
            int kv = kv0 + n * 32 + (r & 3) + 8 * (r >> 2) + 4 * hi;
            if (kv > qg) sacc[n][r] = -1e30f;
          }
      }
      float pm = -1e30f;
#pragma unroll
      for (int n = 0; n < 2; ++n)
#pragma unroll
        for (int r = 0; r < 16; ++r) pm = fmaxf(pm, sacc[n][r]);
      pm = fmaxf(pm, __shfl_xor(pm, 32));
      if (!__all(pm - m <= 11.0f)) {  // defer-max, log2 units (P <= 2^11)
        float mn = fmaxf(m, pm);
        float sc = exp2_fast(m - mn);
        m = mn;
        lsum *= sc;
#pragma unroll
        for (int r = 0; r < 16; ++r) {
          int row = (r & 3) + 8 * (r >> 2) + 4 * hi;
          float scr = __shfl(sc, row);
#pragma unroll
          for (int d = 0; d < 4; ++d) yacc[d][r] *= scr;
        }
      }
      float ls = 0.f;
#pragma unroll
      for (int n = 0; n < 2; ++n)
#pragma unroll
        for (int r = 0; r < 16; ++r) {
          float e = exp2_fast(sacc[n][r] - m);
          sacc[n][r] = e;
          ls += e;
        }
      ls += __shfl_xor(ls, 32);
      lsum += ls;
      bf16x8 pa[4];
#pragma unroll
      for (int s4 = 0; s4 < 4; ++s4) {
        const int n = s4 >> 1, R = (s4 & 1) * 8;
        unsigned P01 = cvtpk(sacc[n][R + 0], sacc[n][R + 1]);
        unsigned P23 = cvtpk(sacc[n][R + 2], sacc[n][R + 3]);
        unsigned P45 = cvtpk(sacc[n][R + 4], sacc[n][R + 5]);
        unsigned P67 = cvtpk(sacc[n][R + 6], sacc[n][R + 7]);
        plane32_swap(P01, P45);
        plane32_swap(P23, P67);
        union { u32x4 u; bf16x8 bv; } cvu;
        cvu.u[0] = P01; cvu.u[1] = P23; cvu.u[2] = P45; cvu.u[3] = P67;
        pa[s4] = cvu.bv;
      }
      __builtin_amdgcn_s_setprio(1);
#pragma unroll
      for (int d = 0; d < 4; ++d) {
        const int rv = d * 32 + ql;
#pragma unroll
        for (int ks = 0; ks < 4; ++ks) {
          bf16x8 vf = *(const bf16x8*)&Vc[rv * 64 + (((ks * 2 + hi) ^ (rv & 7)) * 8)];
          yacc[d] = __builtin_amdgcn_mfma_f32_32x32x16_bf16(pa[ks], vf, yacc[d], 0, 0, 0);
        }
      }
      __builtin_amdgcn_s_setprio(0);
    }
    cur ^= 1;
  }
#pragma unroll
  for (int r = 0; r < 16; ++r) {
    int row = (r & 3) + 8 * (r >> 2) + 4 * hi;
    float li = __shfl(lsum, row);
    float inv = 1.0f / li;
    u16* yp = yb + ((size_t)(b * 2048) + wq0 + row) * 2048 + h * 128 + ql;
#pragma unroll
    for (int d = 0; d < 4; ++d) yp[d * 32] = f2bf(yacc[d][r] * inv);
  }
}

// ---------------- launcher ----------------

extern "C" void kernel_launch(void* const* d_in, const int* in_sizes, int n_in,
                              void* d_out, int out_size, void* d_ws, size_t ws_size,
                              hipStream_t stream) {
  const float* x    = (const float*)d_in[0];
  const float* Wq   = (const float*)d_in[1];
  const float* Wk   = (const float*)d_in[2];
  const float* Wv   = (const float*)d_in[3];
  const float* Wo   = (const float*)d_in[4];
  const float* qn   = (const float*)d_in[5];
  const float* kn   = (const float*)d_in[6];
  const float* cosb = (const float*)d_in[7];
  const float* sinb = (const float*)d_in[8];
  float* out = (float*)d_out;
  (void)in_sizes; (void)n_in; (void)out_size; (void)ws_size;

  char* p = (char*)d_ws;
  u16*   xb   = (u16*)p;   p += (size_t)8388608 * 2;    // x bf16 [4096,2048]
  u16*   wcat = (u16*)p;   p += (size_t)6291456 * 2;    // [3072,2048]
  u16*   wob  = (u16*)p;   p += (size_t)4194304 * 2;    // [2048,2048]
  float* qkvf = (float*)p; p += (size_t)12582912 * 4;   // [4096,3072] fp32
  u16*   qh   = (u16*)p;   p += (size_t)8388608 * 2;    // [2,16,2048,128]
  u16*   kh   = (u16*)p;   p += (size_t)2097152 * 2;    // [2,4,2048,128]
  u16*   vt   = (u16*)p;   p += (size_t)2097152 * 2;    // [2,4,128,2048]
  u16*   yb   = (u16*)p;   p += (size_t)8388608 * 2;    // [4096,2048]

  cvt_f32_bf16<<<2048, 256, 0, stream>>>(x, xb, 8388608);
  build_wcat<<<2048, 256, 0, stream>>>(Wq, Wk, Wv, wcat);
  cvt_f32_bf16<<<2048, 256, 0, stream>>>(Wo, wob, 4194304);
  gemm_bt<<<768, 256, 0, stream>>>(xb, wcat, qkvf, 4096, 3072, 2048);
  norm_rope<<<20480, 256, 0, stream>>>(qkvf, qn, kn, cosb, sinb, qh, kh);
  v_trans<<<256, 256, 0, stream>>>(qkvf, vt);
  attn<<<256, 512, 0, stream>>>(qh, kh, vt, yb);
  gemm_bt<<<512, 256, 0, stream>>>(yb, wob, out, 4096, 2048, 2048);
}

// Round 14
// 215.367 us; speedup vs baseline: 1.3461x; 1.1059x over previous
//
#include <hip/hip_runtime.h>
#include <stdint.h>

typedef unsigned short u16;
typedef __attribute__((ext_vector_type(4))) float f32x4;
typedef __attribute__((ext_vector_type(16))) float f32x16;
typedef __attribute__((ext_vector_type(8))) short bf16x8;
typedef __attribute__((ext_vector_type(4))) unsigned short u16x4;
typedef __attribute__((ext_vector_type(4))) unsigned u32x4;

static __device__ __forceinline__ u16 f2bf(float f) {
  union { float f; unsigned u; } v; v.f = f;
  unsigned r = v.u + 0x7fffu + ((v.u >> 16) & 1u);
  return (u16)(r >> 16);
}
static __device__ __forceinline__ float bf2f(u16 u) {
  union { unsigned u; float f; } v; v.u = ((unsigned)u) << 16;
  return v.f;
}

static __device__ __forceinline__ unsigned cvtpk(float lo, float hi) {
  unsigned r;
  asm("v_cvt_pk_bf16_f32 %0, %1, %2" : "=v"(r) : "v"(lo), "v"(hi));
  return r;
}

static __device__ __forceinline__ void plane32_swap(unsigned& a, unsigned& b) {
  asm volatile("v_permlane32_swap_b32 %0, %1" : "+v"(a), "+v"(b));
}

static __device__ __forceinline__ float exp2_fast(float x) {
  float r;
  asm("v_exp_f32 %0, %1" : "=v"(r) : "v"(x));
  return r;
}

static __device__ __forceinline__ void load_lds16(const void* g, void* l) {
  __builtin_amdgcn_global_load_lds(
      (const __attribute__((address_space(1))) void*)g,
      (__attribute__((address_space(3))) void*)l, 16, 0, 0);
}

// ---------------- conversion kernels ----------------

__global__ __launch_bounds__(256) void cvt_f32_bf16(
    const float* __restrict__ in, u16* __restrict__ out, int n) {
  int i = blockIdx.x * 256 + threadIdx.x;
  const int n4 = n >> 2;
  for (; i < n4; i += gridDim.x * 256) {
    f32x4 v = *(const f32x4*)(in + (size_t)i * 4);
    u16x4 o = { f2bf(v[0]), f2bf(v[1]), f2bf(v[2]), f2bf(v[3]) };
    *(u16x4*)(out + (size_t)i * 4) = o;
  }
}

__global__ __launch_bounds__(256) void build_wcat(
    const float* __restrict__ Wq, const float* __restrict__ Wk,
    const float* __restrict__ Wv, u16* __restrict__ out) {
  int i = blockIdx.x * 256 + threadIdx.x;
  const int n4 = 3072 * 512;
  for (; i < n4; i += gridDim.x * 256) {
    int row = i >> 9;
    int c4 = i & 511;
    const float* src;
    if (row < 2048)       src = Wq + (size_t)row * 2048;
    else if (row < 2560)  src = Wk + (size_t)(row - 2048) * 2048;
    else                  src = Wv + (size_t)(row - 2560) * 2048;
    f32x4 v = *(const f32x4*)(src + c4 * 4);
    u16x4 o = { f2bf(v[0]), f2bf(v[1]), f2bf(v[2]), f2bf(v[3]) };
    *(u16x4*)(out + (size_t)i * 4) = o;
  }
}

// ======== BK=64 32x32x16 GEMM core (shared by both GEMMs) =========================
// LDS rows are 128 B (exactly 32 banks) -> chunk swizzle c ^= (row&7) makes every
// 8-consecutive-lane phase of a ds_read_b128 cover 8 distinct bank quads: conflict-free
// (R13's BK=32 64B rows could not: 1.9e7 conflicts). Staging: pre-swizzled GLOBAL chunk
// + linear LDS dest (rule 21). 32 K-tiles -> half the barrier drains of BK=32.
#define GEMM_CORE(C_STORE)                                                            \
  __shared__ u16 As[128 * 64];                                                        \
  __shared__ u16 Bs[128 * 64];                                                        \
  const int tid = threadIdx.x;                                                        \
  const int lin = blockIdx.x;                                                         \
  const int x = lin & 7, t = lin >> 3; /* bid%8 == XCD */                             \
  const int bm = x * 4 + (t & 3);                                                     \
  const int bn = t >> 2;                                                              \
  const int w = tid >> 6, l = tid & 63;                                               \
  const int wr = w >> 1, wc = w & 1;                                                  \
  const int ql = l & 31, hi = l >> 5;                                                 \
  f32x16 acc[2][2] = {};                                                              \
  const int nk = K >> 6;                                                              \
  for (int kt = 0; kt < nk; ++kt) {                                                   \
    __syncthreads();                                                                  \
    const int ko = kt << 6;                                                           \
    _Pragma("unroll")                                                                 \
    for (int j = 0; j < 4; ++j) {                                                     \
      int idx = j * 256 + tid;                                                        \
      int row = idx >> 3, ch = idx & 7;                                               \
      int col = ko + (((ch ^ (row & 7))) << 3);                                       \
      load_lds16(A + (size_t)(bm * 128 + row) * K + col, As + idx * 8);               \
      load_lds16(B + (size_t)(bn * 128 + row) * K + col, Bs + idx * 8);               \
    }                                                                                 \
    __syncthreads();                                                                  \
    _Pragma("unroll")                                                                 \
    for (int ks = 0; ks < 4; ++ks) {                                                  \
      const int e = ks * 2 + hi;                                                      \
      bf16x8 af[2], bfr[2];                                                           \
      _Pragma("unroll")                                                               \
      for (int ti = 0; ti < 2; ++ti) {                                                \
        const int ra = wr * 64 + ti * 32 + ql;                                        \
        const int rb = wc * 64 + ti * 32 + ql;                                        \
        af[ti]  = *(const bf16x8*)&As[ra * 64 + ((e ^ (ra & 7)) << 3)];               \
        bfr[ti] = *(const bf16x8*)&Bs[rb * 64 + ((e ^ (rb & 7)) << 3)];               \
      }                                                                               \
      _Pragma("unroll")                                                               \
      for (int mi = 0; mi < 2; ++mi)                                                  \
        _Pragma("unroll")                                                             \
        for (int ni = 0; ni < 2; ++ni)                                                \
          acc[mi][ni] = __builtin_amdgcn_mfma_f32_32x32x16_bf16(                      \
              af[mi], bfr[ni], acc[mi][ni], 0, 0, 0);                                 \
    }                                                                                 \
  }                                                                                   \
  _Pragma("unroll")                                                                   \
  for (int mi = 0; mi < 2; ++mi) {                                                    \
    const int rb0 = bm * 128 + wr * 64 + mi * 32;                                     \
    _Pragma("unroll")                                                                 \
    for (int ni = 0; ni < 2; ++ni) {                                                  \
      const int col = bn * 128 + wc * 64 + ni * 32 + ql;                              \
      _Pragma("unroll")                                                               \
      for (int r = 0; r < 16; ++r) {                                                  \
        const int row = rb0 + (r & 3) + 8 * (r >> 2) + 4 * hi;                        \
        C_STORE;                                                                      \
      }                                                                               \
    }                                                                                 \
  }

// gemm1: C in bf16 (feeds norm_rope/v_trans; halves write traffic)
__global__ __launch_bounds__(256) void gemm_bt16(
    const u16* __restrict__ A, const u16* __restrict__ B,
    u16* __restrict__ C, int M, int N, int K) {
  GEMM_CORE(C[(size_t)row * N + col] = f2bf(acc[mi][ni][r]))
}

// gemm2: C in fp32 (final output)
__global__ __launch_bounds__(256) void gemm_bt(
    const u16* __restrict__ A, const u16* __restrict__ B,
    float* __restrict__ C, int M, int N, int K) {
  GEMM_CORE(C[(size_t)row * N + col] = acc[mi][ni][r])
}

// ---------------- per-head RMSNorm + RoPE (bf16 input; q scaled by 1/(sqrt(128)ln2)) --
__global__ __launch_bounds__(256) void norm_rope(
    const u16* __restrict__ qkv, const float* __restrict__ qn_w,
    const float* __restrict__ kn_w, const float* __restrict__ cosb,
    const float* __restrict__ sinb, u16* __restrict__ qhat,
    u16* __restrict__ khat) {
  const int gw = (blockIdx.x * 256 + threadIdx.x) >> 6;
  const int lane = threadIdx.x & 63;
  const int slot = gw % 20;
  const int row = gw / 20;  // b*2048 + t
  const int t = row & 2047;
  const int b = row >> 11;
  const u16* src; const float* nw; u16* dst;
  bool isq = slot < 16;
  if (isq) {
    src = qkv + (size_t)row * 3072 + slot * 128;
    nw = qn_w;
    dst = qhat + ((size_t)(b * 16 + slot) * 2048 + t) * 128;
  } else {
    src = qkv + (size_t)row * 3072 + 2048 + (slot - 16) * 128;
    nw = kn_w;
    dst = khat + ((size_t)(b * 4 + (slot - 16)) * 2048 + t) * 128;
  }
  float x1 = bf2f(src[lane]), x2 = bf2f(src[lane + 64]);
  float ss = x1 * x1 + x2 * x2;
#pragma unroll
  for (int o = 32; o; o >>= 1) ss += __shfl_xor(ss, o);
  float rs = rsqrtf(ss * (1.0f / 128.0f) + 1e-6f);
  float h1 = x1 * rs * nw[lane];
  float h2 = x2 * rs * nw[lane + 64];
  float c = cosb[t * 128 + lane], s = sinb[t * 128 + lane];
  float o1 = h1 * c - h2 * s;
  float o2 = h2 * c + h1 * s;
  if (isq) { o1 *= 0.12751744752f; o2 *= 0.12751744752f; }  // 1/(sqrt(128)*ln2)
  dst[lane] = f2bf(o1);
  dst[lane + 64] = f2bf(o2);
}

// ---------------- V transpose: qkv bf16 [.,3072] v-cols -> vT bf16 [B,KV,D,T] ---------
__global__ __launch_bounds__(256) void v_trans(
    const u16* __restrict__ qkv, u16* __restrict__ vT) {
  __shared__ u16 st[64][130];
  const int bi = blockIdx.x;
  const int tt = bi & 31;
  const int kv = (bi >> 5) & 3;
  const int b = bi >> 7;
  const int tid = threadIdx.x;
#pragma unroll
  for (int i = 0; i < 32; ++i) {
    int idx = i * 256 + tid;
    int t = idx >> 7, d = idx & 127;
    st[t][d] = qkv[(size_t)(b * 2048 + tt * 64 + t) * 3072 + 2560 + kv * 128 + d];
  }
  __syncthreads();
#pragma unroll
  for (int i = 0; i < 32; ++i) {
    int idx = i * 256 + tid;
    int d = idx >> 6, t = idx & 63;
    vT[((size_t)(b * 4 + kv) * 128 + d) * 2048 + tt * 64 + t] = st[t][d];
  }
}

// ---------------- causal GQA flash attention (R12 verified: 8-warp, K+V in LDS) -------
__global__ __launch_bounds__(512, 2) void attn(
    const u16* __restrict__ qhat, const u16* __restrict__ khat,
    const u16* __restrict__ vT, u16* __restrict__ yb) {
  __shared__ u16 Kt[2][64 * 128];   // 32 KB
  __shared__ u16 Vt[2][128 * 64];   // 32 KB  (rows = d 0..127, cols = 64 kv)
  const int bi = blockIdx.x;        // bh*8 + s
  const int s = bi & 7;
  const int bh = bi >> 3;
  const int h = bh & 15, b = bh >> 4;
  const int kvh = h >> 2;
  const int tid = threadIdx.x;
  const int w = tid >> 6, l = tid & 63;
  const int ws = w & 3;
  const int cw = (w < 4) ? s : (15 - s);
  const int ql = l & 31, hi = l >> 5;
  const int wq0 = cw * 128 + ws * 32;
  const int wq_end = wq0 + 31;
  const int qg = wq0 + ql;

  bf16x8 qf[8];
  const u16* qp = qhat + ((size_t)(b * 16 + h) * 2048 + qg) * 128 + hi * 8;
#pragma unroll
  for (int sf = 0; sf < 8; ++sf) qf[sf] = *(const bf16x8*)(qp + 16 * sf);

  f32x16 yacc[4] = {};
  float m = -1e30f, lsum = 0.f;

  const u16* Kg = khat + (size_t)(b * 4 + kvh) * 2048 * 128;
  const u16* Vg = vT + (size_t)(b * 4 + kvh) * 128 * 2048;
  const int nt = 32 - 2 * s;

  auto stageK = [&](int tile, int buf) {
#pragma unroll
    for (int j = 0; j < 2; ++j) {
      int idx = j * 512 + tid;
      int row = idx >> 4, ch = idx & 15;
      load_lds16(Kg + (size_t)(tile * 64 + row) * 128 + ((ch ^ (row & 7)) * 8),
                 &Kt[buf][idx * 8]);
    }
  };
  auto stageV = [&](int tile, int buf) {
#pragma unroll
    for (int j = 0; j < 2; ++j) {
      int idx = j * 512 + tid;
      int row = idx >> 3, ch = idx & 7;
      load_lds16(Vg + (size_t)row * 2048 + tile * 64 + ((ch ^ (row & 7)) * 8),
                 &Vt[buf][idx * 8]);
    }
  };

  stageK(0, 0);
  stageV(0, 0);
  int cur = 0;
  for (int tile = 0; tile < nt; ++tile) {
    const int kv0 = tile * 64;
    __syncthreads();
    if (tile + 1 < nt) { stageK(tile + 1, cur ^ 1); stageV(tile + 1, cur ^ 1); }
    if (kv0 <= wq_end) {
      const u16* Kc = Kt[cur];
      const u16* Vc = Vt[cur];
      f32x16 sacc[2] = {};
      __builtin_amdgcn_s_setprio(1);
#pragma unroll
      for (int n = 0; n < 2; ++n) {
#pragma unroll
        for (int sf = 0; sf < 8; ++sf) {
          bf16x8 kf = *(const bf16x8*)&Kc[(n * 32 + ql) * 128 + (((2 * sf + hi) ^ (l & 7)) * 8)];
          sacc[n] = __builtin_amdgcn_mfma_f32_32x32x16_bf16(kf, qf[sf], sacc[n], 0, 0, 0);
        }
      }
      __builtin_amdgcn_s_setprio(0);
      if (kv0 + 63 > wq0) {
#pragma unroll
        for (int n = 0; n < 2; ++n)
#pragma unroll
          for (int r = 0; r < 16; ++r) {
            int kv = kv0 + n * 32 + (r & 3) + 8 * (r >> 2) + 4 * hi;
            if (kv > qg) sacc[n][r] = -1e30f;
          }
      }
      float pm = -1e30f;
#pragma unroll
      for (int n = 0; n < 2; ++n)
#pragma unroll
        for (int r = 0; r < 16; ++r) pm = fmaxf(pm, sacc[n][r]);
      pm = fmaxf(pm, __shfl_xor(pm, 32));
      if (!__all(pm - m <= 11.0f)) {  // defer-max, log2 units (P <= 2^11)
        float mn = fmaxf(m, pm);
        float sc = exp2_fast(m - mn);
        m = mn;
        lsum *= sc;
#pragma unroll
        for (int r = 0; r < 16; ++r) {
          int row = (r & 3) + 8 * (r >> 2) + 4 * hi;
          float scr = __shfl(sc, row);
#pragma unroll
          for (int d = 0; d < 4; ++d) yacc[d][r] *= scr;
        }
      }
      float ls = 0.f;
#pragma unroll
      for (int n = 0; n < 2; ++n)
#pragma unroll
        for (int r = 0; r < 16; ++r) {
          float e = exp2_fast(sacc[n][r] - m);
          sacc[n][r] = e;
          ls += e;
        }
      ls += __shfl_xor(ls, 32);
      lsum += ls;
      bf16x8 pa[4];
#pragma unroll
      for (int s4 = 0; s4 < 4; ++s4) {
        const int n = s4 >> 1, R = (s4 & 1) * 8;
        unsigned P01 = cvtpk(sacc[n][R + 0], sacc[n][R + 1]);
        unsigned P23 = cvtpk(sacc[n][R + 2], sacc[n][R + 3]);
        unsigned P45 = cvtpk(sacc[n][R + 4], sacc[n][R + 5]);
        unsigned P67 = cvtpk(sacc[n][R + 6], sacc[n][R + 7]);
        plane32_swap(P01, P45);
        plane32_swap(P23, P67);
        union { u32x4 u; bf16x8 bv; } cvu;
        cvu.u[0] = P01; cvu.u[1] = P23; cvu.u[2] = P45; cvu.u[3] = P67;
        pa[s4] = cvu.bv;
      }
      __builtin_amdgcn_s_setprio(1);
#pragma unroll
      for (int d = 0; d < 4; ++d) {
        const int rv = d * 32 + ql;
#pragma unroll
        for (int ks = 0; ks < 4; ++ks) {
          bf16x8 vf = *(const bf16x8*)&Vc[rv * 64 + (((ks * 2 + hi) ^ (rv & 7)) * 8)];
          yacc[d] = __builtin_amdgcn_mfma_f32_32x32x16_bf16(pa[ks], vf, yacc[d], 0, 0, 0);
        }
      }
      __builtin_amdgcn_s_setprio(0);
    }
    cur ^= 1;
  }
#pragma unroll
  for (int r = 0; r < 16; ++r) {
    int row = (r & 3) + 8 * (r >> 2) + 4 * hi;
    float li = __shfl(lsum, row);
    float inv = 1.0f / li;
    u16* yp = yb + ((size_t)(b * 2048) + wq0 + row) * 2048 + h * 128 + ql;
#pragma unroll
    for (int d = 0; d < 4; ++d) yp[d * 32] = f2bf(yacc[d][r] * inv);
  }
}

// ---------------- launcher ----------------

extern "C" void kernel_launch(void* const* d_in, const int* in_sizes, int n_in,
                              void* d_out, int out_size, void* d_ws, size_t ws_size,
                              hipStream_t stream) {
  const float* x    = (const float*)d_in[0];
  const float* Wq   = (const float*)d_in[1];
  const float* Wk   = (const float*)d_in[2];
  const float* Wv   = (const float*)d_in[3];
  const float* Wo   = (const float*)d_in[4];
  const float* qn   = (const float*)d_in[5];
  const float* kn   = (const float*)d_in[6];
  const float* cosb = (const float*)d_in[7];
  const float* sinb = (const float*)d_in[8];
  float* out = (float*)d_out;
  (void)in_sizes; (void)n_in; (void)out_size; (void)ws_size;

  char* p = (char*)d_ws;
  u16*   xb   = (u16*)p;   p += (size_t)8388608 * 2;    // x bf16 [4096,2048]
  u16*   wcat = (u16*)p;   p += (size_t)6291456 * 2;    // [3072,2048]
  u16*   wob  = (u16*)p;   p += (size_t)4194304 * 2;    // [2048,2048]
  u16*   qkvb = (u16*)p;   p += (size_t)12582912 * 2;   // [4096,3072] bf16
  u16*   qh   = (u16*)p;   p += (size_t)8388608 * 2;    // [2,16,2048,128]
  u16*   kh   = (u16*)p;   p += (size_t)2097152 * 2;    // [2,4,2048,128]
  u16*   vt   = (u16*)p;   p += (size_t)2097152 * 2;    // [2,4,128,2048]
  u16*   yb   = (u16*)p;   p += (size_t)8388608 * 2;    // [4096,2048]

  cvt_f32_bf16<<<2048, 256, 0, stream>>>(x, xb, 8388608);
  build_wcat<<<2048, 256, 0, stream>>>(Wq, Wk, Wv, wcat);
  cvt_f32_bf16<<<2048, 256, 0, stream>>>(Wo, wob, 4194304);
  gemm_bt16<<<768, 256, 0, stream>>>(xb, wcat, qkvb, 4096, 3072, 2048);
  norm_rope<<<20480, 256, 0, stream>>>(qkvb, qn, kn, cosb, sinb, qh, kh);
  v_trans<<<256, 256, 0, stream>>>(qkvb, vt);
  attn<<<256, 512, 0, stream>>>(qh, kh, vt, yb);
  gemm_bt<<<512, 256, 0, stream>>>(yb, wob, out, 4096, 2048, 2048);
}

// Round 15
// 211.964 us; speedup vs baseline: 1.3677x; 1.0161x over previous
//
#include <hip/hip_runtime.h>
#include <stdint.h>

typedef unsigned short u16;
typedef __attribute__((ext_vector_type(4))) float f32x4;
typedef __attribute__((ext_vector_type(16))) float f32x16;
typedef __attribute__((ext_vector_type(8))) short bf16x8;
typedef __attribute__((ext_vector_type(4))) unsigned short u16x4;
typedef __attribute__((ext_vector_type(4))) unsigned u32x4;

static __device__ __forceinline__ u16 f2bf(float f) {
  union { float f; unsigned u; } v; v.f = f;
  unsigned r = v.u + 0x7fffu + ((v.u >> 16) & 1u);
  return (u16)(r >> 16);
}
static __device__ __forceinline__ float bf2f(u16 u) {
  union { unsigned u; float f; } v; v.u = ((unsigned)u) << 16;
  return v.f;
}

static __device__ __forceinline__ unsigned cvtpk(float lo, float hi) {
  unsigned r;
  asm("v_cvt_pk_bf16_f32 %0, %1, %2" : "=v"(r) : "v"(lo), "v"(hi));
  return r;
}

static __device__ __forceinline__ void plane32_swap(unsigned& a, unsigned& b) {
  asm volatile("v_permlane32_swap_b32 %0, %1" : "+v"(a), "+v"(b));
}

static __device__ __forceinline__ float exp2_fast(float x) {
  float r;
  asm("v_exp_f32 %0, %1" : "=v"(r) : "v"(x));
  return r;
}

static __device__ __forceinline__ void load_lds16(const void* g, void* l) {
  __builtin_amdgcn_global_load_lds(
      (const __attribute__((address_space(1))) void*)g,
      (__attribute__((address_space(3))) void*)l, 16, 0, 0);
}

// ---------------- conversion kernels ----------------

__global__ __launch_bounds__(256) void cvt_f32_bf16(
    const float* __restrict__ in, u16* __restrict__ out, int n) {
  int i = blockIdx.x * 256 + threadIdx.x;
  const int n4 = n >> 2;
  for (; i < n4; i += gridDim.x * 256) {
    f32x4 v = *(const f32x4*)(in + (size_t)i * 4);
    u16x4 o = { f2bf(v[0]), f2bf(v[1]), f2bf(v[2]), f2bf(v[3]) };
    *(u16x4*)(out + (size_t)i * 4) = o;
  }
}

__global__ __launch_bounds__(256) void build_wcat(
    const float* __restrict__ Wq, const float* __restrict__ Wk,
    const float* __restrict__ Wv, u16* __restrict__ out) {
  int i = blockIdx.x * 256 + threadIdx.x;
  const int n4 = 3072 * 512;
  for (; i < n4; i += gridDim.x * 256) {
    int row = i >> 9;
    int c4 = i & 511;
    const float* src;
    if (row < 2048)       src = Wq + (size_t)row * 2048;
    else if (row < 2560)  src = Wk + (size_t)(row - 2048) * 2048;
    else                  src = Wv + (size_t)(row - 2560) * 2048;
    f32x4 v = *(const f32x4*)(src + c4 * 4);
    u16x4 o = { f2bf(v[0]), f2bf(v[1]), f2bf(v[2]), f2bf(v[3]) };
    *(u16x4*)(out + (size_t)i * 4) = o;
  }
}

// ======== BK=64 32x32x16 GEMM core (shared by both GEMMs) =========================
// 128 B LDS rows; chunk swizzle c ^= (row&7) -> conflict-free ds_read_b128.
// Pre-swizzled GLOBAL chunk + linear LDS dest (rule 21). XCD-localized bm.
#define GEMM_CORE(C_STORE)                                                            \
  __shared__ u16 As[128 * 64];                                                        \
  __shared__ u16 Bs[128 * 64];                                                        \
  const int tid = threadIdx.x;                                                        \
  const int lin = blockIdx.x;                                                         \
  const int x = lin & 7, t = lin >> 3; /* bid%8 == XCD */                             \
  const int bm = x * 4 + (t & 3);                                                     \
  const int bn = t >> 2;                                                              \
  const int w = tid >> 6, l = tid & 63;                                               \
  const int wr = w >> 1, wc = w & 1;                                                  \
  const int ql = l & 31, hi = l >> 5;                                                 \
  f32x16 acc[2][2] = {};                                                              \
  const int nk = K >> 6;                                                              \
  for (int kt = 0; kt < nk; ++kt) {                                                   \
    __syncthreads();                                                                  \
    const int ko = kt << 6;                                                           \
    _Pragma("unroll")                                                                 \
    for (int j = 0; j < 4; ++j) {                                                     \
      int idx = j * 256 + tid;                                                        \
      int row = idx >> 3, ch = idx & 7;                                               \
      int col = ko + (((ch ^ (row & 7))) << 3);                                       \
      load_lds16(A + (size_t)(bm * 128 + row) * K + col, As + idx * 8);               \
      load_lds16(B + (size_t)(bn * 128 + row) * K + col, Bs + idx * 8);               \
    }                                                                                 \
    __syncthreads();                                                                  \
    _Pragma("unroll")                                                                 \
    for (int ks = 0; ks < 4; ++ks) {                                                  \
      const int e = ks * 2 + hi;                                                      \
      bf16x8 af[2], bfr[2];                                                           \
      _Pragma("unroll")                                                               \
      for (int ti = 0; ti < 2; ++ti) {                                                \
        const int ra = wr * 64 + ti * 32 + ql;                                        \
        const int rb = wc * 64 + ti * 32 + ql;                                        \
        af[ti]  = *(const bf16x8*)&As[ra * 64 + ((e ^ (ra & 7)) << 3)];               \
        bfr[ti] = *(const bf16x8*)&Bs[rb * 64 + ((e ^ (rb & 7)) << 3)];               \
      }                                                                               \
      _Pragma("unroll")                                                               \
      for (int mi = 0; mi < 2; ++mi)                                                  \
        _Pragma("unroll")                                                             \
        for (int ni = 0; ni < 2; ++ni)                                                \
          acc[mi][ni] = __builtin_amdgcn_mfma_f32_32x32x16_bf16(                      \
              af[mi], bfr[ni], acc[mi][ni], 0, 0, 0);                                 \
    }                                                                                 \
  }                                                                                   \
  _Pragma("unroll")                                                                   \
  for (int mi = 0; mi < 2; ++mi) {                                                    \
    const int rb0 = bm * 128 + wr * 64 + mi * 32;                                     \
    _Pragma("unroll")                                                                 \
    for (int ni = 0; ni < 2; ++ni) {                                                  \
      const int col = bn * 128 + wc * 64 + ni * 32 + ql;                              \
      _Pragma("unroll")                                                               \
      for (int r = 0; r < 16; ++r) {                                                  \
        const int row = rb0 + (r & 3) + 8 * (r >> 2) + 4 * hi;                        \
        C_STORE;                                                                      \
      }                                                                               \
    }                                                                                 \
  }

// gemm1: C in bf16 (feeds norm_rope/v_trans; halves write traffic)
__global__ __launch_bounds__(256) void gemm_bt16(
    const u16* __restrict__ A, const u16* __restrict__ B,
    u16* __restrict__ C, int M, int N, int K) {
  GEMM_CORE(C[(size_t)row * N + col] = f2bf(acc[mi][ni][r]))
}

// gemm2: C in fp32 (final output)
__global__ __launch_bounds__(256) void gemm_bt(
    const u16* __restrict__ A, const u16* __restrict__ B,
    float* __restrict__ C, int M, int N, int K) {
  GEMM_CORE(C[(size_t)row * N + col] = acc[mi][ni][r])
}

// ---------------- per-head RMSNorm + RoPE (bf16 input; q scaled by 1/(sqrt(128)ln2)) --
__global__ __launch_bounds__(256) void norm_rope(
    const u16* __restrict__ qkv, const float* __restrict__ qn_w,
    const float* __restrict__ kn_w, const float* __restrict__ cosb,
    const float* __restrict__ sinb, u16* __restrict__ qhat,
    u16* __restrict__ khat) {
  const int gw = (blockIdx.x * 256 + threadIdx.x) >> 6;
  const int lane = threadIdx.x & 63;
  const int slot = gw % 20;
  const int row = gw / 20;  // b*2048 + t
  const int t = row & 2047;
  const int b = row >> 11;
  const u16* src; const float* nw; u16* dst;
  bool isq = slot < 16;
  if (isq) {
    src = qkv + (size_t)row * 3072 + slot * 128;
    nw = qn_w;
    dst = qhat + ((size_t)(b * 16 + slot) * 2048 + t) * 128;
  } else {
    src = qkv + (size_t)row * 3072 + 2048 + (slot - 16) * 128;
    nw = kn_w;
    dst = khat + ((size_t)(b * 4 + (slot - 16)) * 2048 + t) * 128;
  }
  float x1 = bf2f(src[lane]), x2 = bf2f(src[lane + 64]);
  float ss = x1 * x1 + x2 * x2;
#pragma unroll
  for (int o = 32; o; o >>= 1) ss += __shfl_xor(ss, o);
  float rs = rsqrtf(ss * (1.0f / 128.0f) + 1e-6f);
  float h1 = x1 * rs * nw[lane];
  float h2 = x2 * rs * nw[lane + 64];
  float c = cosb[t * 128 + lane], s = sinb[t * 128 + lane];
  float o1 = h1 * c - h2 * s;
  float o2 = h2 * c + h1 * s;
  if (isq) { o1 *= 0.12751744752f; o2 *= 0.12751744752f; }  // 1/(sqrt(128)*ln2)
  dst[lane] = f2bf(o1);
  dst[lane + 64] = f2bf(o2);
}

// ---------------- V transpose: qkv bf16 [.,3072] v-cols -> vT bf16 [B,KV,D,T] ---------
__global__ __launch_bounds__(256) void v_trans(
    const u16* __restrict__ qkv, u16* __restrict__ vT) {
  __shared__ u16 st[64][130];
  const int bi = blockIdx.x;
  const int tt = bi & 31;
  const int kv = (bi >> 5) & 3;
  const int b = bi >> 7;
  const int tid = threadIdx.x;
#pragma unroll
  for (int i = 0; i < 32; ++i) {
    int idx = i * 256 + tid;
    int t = idx >> 7, d = idx & 127;
    st[t][d] = qkv[(size_t)(b * 2048 + tt * 64 + t) * 3072 + 2560 + kv * 128 + d];
  }
  __syncthreads();
#pragma unroll
  for (int i = 0; i < 32; ++i) {
    int idx = i * 256 + tid;
    int d = idx >> 6, t = idx & 63;
    vT[((size_t)(b * 4 + kv) * 128 + d) * 2048 + tt * 64 + t] = st[t][d];
  }
}

// ---------------- causal GQA flash attention (4-warp blocks, 2 blocks/CU) -------------
// R14 diagnosis: grid 256 = 1 block/CU -> every __syncthreads stalls the whole CU.
// Now 512 blocks x 4 warps, one 128-row strip each; blocks bi and bi+256 carry strips
// cc and 15-cc of the same (b,h) (uniform 34-tile pairs, shared K/V in L2) and run
// phase-skewed on one CU -> one block computes while the other waits at its barrier.
// Per-warp algorithm identical to R12-R14 (K+V LDS dbuf, swapped 32x32 QK^T, log2 SM).
__global__ __launch_bounds__(256, 2) void attn(
    const u16* __restrict__ qhat, const u16* __restrict__ khat,
    const u16* __restrict__ vT, u16* __restrict__ yb) {
  __shared__ u16 Kt[2][64 * 128];   // 32 KB
  __shared__ u16 Vt[2][128 * 64];   // 32 KB
  const int bi = blockIdx.x;        // [0,512)
  const int j = bi & 255;
  const int pairup = bi >> 8;
  const int bh = j >> 3;            // b*16 + h
  const int cc = j & 7;
  const int c = pairup ? (15 - cc) : cc;   // this block's 128-row strip
  const int h = bh & 15, b = bh >> 4;
  const int kvh = h >> 2;
  const int tid = threadIdx.x;
  const int w = tid >> 6, l = tid & 63;
  const int ql = l & 31, hi = l >> 5;
  const int wq0 = c * 128 + w * 32;
  const int wq_end = wq0 + 31;
  const int qg = wq0 + ql;

  bf16x8 qf[8];
  const u16* qp = qhat + ((size_t)(b * 16 + h) * 2048 + qg) * 128 + hi * 8;
#pragma unroll
  for (int sf = 0; sf < 8; ++sf) qf[sf] = *(const bf16x8*)(qp + 16 * sf);

  f32x16 yacc[4] = {};
  float m = -1e30f, lsum = 0.f;

  const u16* Kg = khat + (size_t)(b * 4 + kvh) * 2048 * 128;
  const u16* Vg = vT + (size_t)(b * 4 + kvh) * 128 * 2048;
  const int nt = 2 * c + 2;         // tiles covering kv <= (c+1)*128

  // stage one K tile (64x128 = 1024 16B-chunks) with 256 threads: 4 chunks each
  auto stageK = [&](int tile, int buf) {
#pragma unroll
    for (int jj = 0; jj < 4; ++jj) {
      int idx = jj * 256 + tid;
      int row = idx >> 4, ch = idx & 15;
      load_lds16(Kg + (size_t)(tile * 64 + row) * 128 + ((ch ^ (row & 7)) * 8),
                 &Kt[buf][idx * 8]);
    }
  };
  auto stageV = [&](int tile, int buf) {
#pragma unroll
    for (int jj = 0; jj < 4; ++jj) {
      int idx = jj * 256 + tid;
      int row = idx >> 3, ch = idx & 7;
      load_lds16(Vg + (size_t)row * 2048 + tile * 64 + ((ch ^ (row & 7)) * 8),
                 &Vt[buf][idx * 8]);
    }
  };

  stageK(0, 0);
  stageV(0, 0);
  int cur = 0;
  for (int tile = 0; tile < nt; ++tile) {
    const int kv0 = tile * 64;
    __syncthreads();
    if (tile + 1 < nt) { stageK(tile + 1, cur ^ 1); stageV(tile + 1, cur ^ 1); }
    if (kv0 <= wq_end) {
      const u16* Kc = Kt[cur];
      const u16* Vc = Vt[cur];
      f32x16 sacc[2] = {};
      __builtin_amdgcn_s_setprio(1);
#pragma unroll
      for (int n = 0; n < 2; ++n) {
#pragma unroll
        for (int sf = 0; sf < 8; ++sf) {
          bf16x8 kf = *(const bf16x8*)&Kc[(n * 32 + ql) * 128 + (((2 * sf + hi) ^ (l & 7)) * 8)];
          sacc[n] = __builtin_amdgcn_mfma_f32_32x32x16_bf16(kf, qf[sf], sacc[n], 0, 0, 0);
        }
      }
      __builtin_amdgcn_s_setprio(0);
      if (kv0 + 63 > wq0) {
#pragma unroll
        for (int n = 0; n < 2; ++n)
#pragma unroll
          for (int r = 0; r < 16; ++r) {
            int kv = kv0 + n * 32 + (r & 3) + 8 * (r >> 2) + 4 * hi;
            if (kv > qg) sacc[n][r] = -1e30f;
          }
      }
      float pm = -1e30f;
#pragma unroll
      for (int n = 0; n < 2; ++n)
#pragma unroll
        for (int r = 0; r < 16; ++r) pm = fmaxf(pm, sacc[n][r]);
      pm = fmaxf(pm, __shfl_xor(pm, 32));
      if (!__all(pm - m <= 11.0f)) {  // defer-max, log2 units (P <= 2^11)
        float mn = fmaxf(m, pm);
        float sc = exp2_fast(m - mn);
        m = mn;
        lsum *= sc;
#pragma unroll
        for (int r = 0; r < 16; ++r) {
          int row = (r & 3) + 8 * (r >> 2) + 4 * hi;
          float scr = __shfl(sc, row);
#pragma unroll
          for (int d = 0; d < 4; ++d) yacc[d][r] *= scr;
        }
      }
      float ls = 0.f;
#pragma unroll
      for (int n = 0; n < 2; ++n)
#pragma unroll
        for (int r = 0; r < 16; ++r) {
          float e = exp2_fast(sacc[n][r] - m);
          sacc[n][r] = e;
          ls += e;
        }
      ls += __shfl_xor(ls, 32);
      lsum += ls;
      bf16x8 pa[4];
#pragma unroll
      for (int s4 = 0; s4 < 4; ++s4) {
        const int n = s4 >> 1, R = (s4 & 1) * 8;
        unsigned P01 = cvtpk(sacc[n][R + 0], sacc[n][R + 1]);
        unsigned P23 = cvtpk(sacc[n][R + 2], sacc[n][R + 3]);
        unsigned P45 = cvtpk(sacc[n][R + 4], sacc[n][R + 5]);
        unsigned P67 = cvtpk(sacc[n][R + 6], sacc[n][R + 7]);
        plane32_swap(P01, P45);
        plane32_swap(P23, P67);
        union { u32x4 u; bf16x8 bv; } cvu;
        cvu.u[0] = P01; cvu.u[1] = P23; cvu.u[2] = P45; cvu.u[3] = P67;
        pa[s4] = cvu.bv;
      }
      __builtin_amdgcn_s_setprio(1);
#pragma unroll
      for (int d = 0; d < 4; ++d) {
        const int rv = d * 32 + ql;
#pragma unroll
        for (int ks = 0; ks < 4; ++ks) {
          bf16x8 vf = *(const bf16x8*)&Vc[rv * 64 + (((ks * 2 + hi) ^ (rv & 7)) * 8)];
          yacc[d] = __builtin_amdgcn_mfma_f32_32x32x16_bf16(pa[ks], vf, yacc[d], 0, 0, 0);
        }
      }
      __builtin_amdgcn_s_setprio(0);
    }
    cur ^= 1;
  }
#pragma unroll
  for (int r = 0; r < 16; ++r) {
    int row = (r & 3) + 8 * (r >> 2) + 4 * hi;
    float li = __shfl(lsum, row);
    float inv = 1.0f / li;
    u16* yp = yb + ((size_t)(b * 2048) + wq0 + row) * 2048 + h * 128 + ql;
#pragma unroll
    for (int d = 0; d < 4; ++d) yp[d * 32] = f2bf(yacc[d][r] * inv);
  }
}

// ---------------- launcher ----------------

extern "C" void kernel_launch(void* const* d_in, const int* in_sizes, int n_in,
                              void* d_out, int out_size, void* d_ws, size_t ws_size,
                              hipStream_t stream) {
  const float* x    = (const float*)d_in[0];
  const float* Wq   = (const float*)d_in[1];
  const float* Wk   = (const float*)d_in[2];
  const float* Wv   = (const float*)d_in[3];
  const float* Wo   = (const float*)d_in[4];
  const float* qn   = (const float*)d_in[5];
  const float* kn   = (const float*)d_in[6];
  const float* cosb = (const float*)d_in[7];
  const float* sinb = (const float*)d_in[8];
  float* out = (float*)d_out;
  (void)in_sizes; (void)n_in; (void)out_size; (void)ws_size;

  char* p = (char*)d_ws;
  u16*   xb   = (u16*)p;   p += (size_t)8388608 * 2;    // x bf16 [4096,2048]
  u16*   wcat = (u16*)p;   p += (size_t)6291456 * 2;    // [3072,2048]
  u16*   wob  = (u16*)p;   p += (size_t)4194304 * 2;    // [2048,2048]
  u16*   qkvb = (u16*)p;   p += (size_t)12582912 * 2;   // [4096,3072] bf16
  u16*   qh   = (u16*)p;   p += (size_t)8388608 * 2;    // [2,16,2048,128]
  u16*   kh   = (u16*)p;   p += (size_t)2097152 * 2;    // [2,4,2048,128]
  u16*   vt   = (u16*)p;   p += (size_t)2097152 * 2;    // [2,4,128,2048]
  u16*   yb   = (u16*)p;   p += (size_t)8388608 * 2;    // [4096,2048]

  cvt_f32_bf16<<<2048, 256, 0, stream>>>(x, xb, 8388608);
  build_wcat<<<2048, 256, 0, stream>>>(Wq, Wk, Wv, wcat);
  cvt_f32_bf16<<<2048, 256, 0, stream>>>(Wo, wob, 4194304);
  gemm_bt16<<<768, 256, 0, stream>>>(xb, wcat, qkvb, 4096, 3072, 2048);
  norm_rope<<<20480, 256, 0, stream>>>(qkvb, qn, kn, cosb, sinb, qh, kh);
  v_trans<<<256, 256, 0, stream>>>(qkvb, vt);
  attn<<<512, 256, 0, stream>>>(qh, kh, vt, yb);
  gemm_bt<<<512, 256, 0, stream>>>(yb, wob, out, 4096, 2048, 2048);
}